// Round 4
// baseline (354.182 us; speedup 1.0000x reference)
//
#include <hip/hip_runtime.h>
#include <hip/hip_bf16.h>
#include <stdint.h>

#define B_N 4
#define NQ 1024
#define NKV 2048
#define DI 1024
#define H 16
#define DH 64

using bf16 = __bf16;
typedef bf16 bf16x8 __attribute__((ext_vector_type(8)));
typedef bf16 bf16x4 __attribute__((ext_vector_type(4)));
typedef float f32x4 __attribute__((ext_vector_type(4)));

typedef const __attribute__((address_space(1))) void* gptr_t;
typedef __attribute__((address_space(3))) void* sptr_t;

// ---------------- f32 -> bf16 convert ----------------
__global__ __launch_bounds__(256) void cvt_kernel(const float* __restrict__ in,
                                                  bf16* __restrict__ out, int n4) {
  int i = blockIdx.x * blockDim.x + threadIdx.x;
  if (i < n4) {
    float4 v = reinterpret_cast<const float4*>(in)[i];
    bf16x4 o;
    o[0] = (bf16)v.x; o[1] = (bf16)v.y; o[2] = (bf16)v.z; o[3] = (bf16)v.w;
    reinterpret_cast<bf16x4*>(out)[i] = o;
  }
}

// ---------------- LayerNorm (rows of 1024 f32) -> bf16 ----------------
__global__ __launch_bounds__(256) void ln_kernel(const float* __restrict__ x,
    const float* __restrict__ gamma, const float* __restrict__ beta,
    bf16* __restrict__ out) {
  int row = blockIdx.x;
  int t = threadIdx.x;
  const float4 v = reinterpret_cast<const float4*>(x + (size_t)row * 1024)[t];
  float s = v.x + v.y + v.z + v.w;
  float s2 = v.x*v.x + v.y*v.y + v.z*v.z + v.w*v.w;
#pragma unroll
  for (int m = 1; m < 64; m <<= 1) { s += __shfl_xor(s, m); s2 += __shfl_xor(s2, m); }
  __shared__ float red[8];
  int wid = t >> 6;
  if ((t & 63) == 0) { red[wid] = s; red[wid + 4] = s2; }
  __syncthreads();
  float ts  = red[0] + red[1] + red[2] + red[3];
  float ts2 = red[4] + red[5] + red[6] + red[7];
  float mean = ts * (1.0f / 1024.0f);
  float var  = ts2 * (1.0f / 1024.0f) - mean * mean;
  float rstd = rsqrtf(var + 1e-5f);
  float4 g  = reinterpret_cast<const float4*>(gamma)[t];
  float4 bb = reinterpret_cast<const float4*>(beta)[t];
  bf16x4 o;
  o[0] = (bf16)((v.x - mean) * rstd * g.x + bb.x);
  o[1] = (bf16)((v.y - mean) * rstd * g.y + bb.y);
  o[2] = (bf16)((v.z - mean) * rstd * g.z + bb.z);
  o[3] = (bf16)((v.w - mean) * rstd * g.w + bb.w);
  reinterpret_cast<bf16x4*>(out + (size_t)row * 1024)[t] = o;
}

// ---------------- GEMM: C[m,n] = sum_k A[m,k]*Bm[n,k]  (A: MxK, Bm: NxK, K=1024) ----
// MODE 0: bf16 out, * (0.125*log2e) (qp, exp2-domain logits)
// MODE 1: kv split -> out0 = K (B,NKV,DI) bf16, out1 = V^T permuted (B,DI,NKV) bf16
// MODE 2: f32 out + bias (proj)
template<int MODE>
__global__ __launch_bounds__(256) void gemm_bt(const bf16* __restrict__ A,
    const bf16* __restrict__ Bm, void* __restrict__ out0, void* __restrict__ out1,
    const float* __restrict__ bias, int M, int N) {
  constexpr int K = 1024;
  __shared__ bf16 lA[128 * 32];
  __shared__ bf16 lB[128 * 32];
  const int nbn = N >> 7;
  const int bm = blockIdx.x / nbn, bn = blockIdx.x - bm * nbn;
  const int m0 = bm << 7, n0 = bn << 7;
  const int tid = threadIdx.x;
  const int lane = tid & 63, wid = tid >> 6;
  const int wr = wid >> 1, wc = wid & 1;
  const int l15 = lane & 15, lg = lane >> 4;

  f32x4 acc[4][4] = {};

  const int c0 = tid, c1 = tid + 256;
  const bf16* gA0 = A  + (size_t)(m0 + (c0 >> 2)) * K + ((c0 & 3) << 3);
  const bf16* gA1 = A  + (size_t)(m0 + (c1 >> 2)) * K + ((c1 & 3) << 3);
  const bf16* gB0 = Bm + (size_t)(n0 + (c0 >> 2)) * K + ((c0 & 3) << 3);
  const bf16* gB1 = Bm + (size_t)(n0 + (c1 >> 2)) * K + ((c1 & 3) << 3);

  for (int k0 = 0; k0 < K; k0 += 32) {
    __builtin_amdgcn_global_load_lds((gptr_t)(gA0 + k0), (sptr_t)(lA + c0 * 8), 16, 0, 0);
    __builtin_amdgcn_global_load_lds((gptr_t)(gA1 + k0), (sptr_t)(lA + c1 * 8), 16, 0, 0);
    __builtin_amdgcn_global_load_lds((gptr_t)(gB0 + k0), (sptr_t)(lB + c0 * 8), 16, 0, 0);
    __builtin_amdgcn_global_load_lds((gptr_t)(gB1 + k0), (sptr_t)(lB + c1 * 8), 16, 0, 0);
    __syncthreads();
    bf16x8 af[4], bfr[4];
#pragma unroll
    for (int i = 0; i < 4; ++i) {
      af[i]  = *reinterpret_cast<const bf16x8*>(lA + (wr * 64 + i * 16 + l15) * 32 + lg * 8);
      bfr[i] = *reinterpret_cast<const bf16x8*>(lB + (wc * 64 + i * 16 + l15) * 32 + lg * 8);
    }
#pragma unroll
    for (int i = 0; i < 4; ++i)
#pragma unroll
      for (int j = 0; j < 4; ++j)
        acc[i][j] = __builtin_amdgcn_mfma_f32_16x16x32_bf16(af[i], bfr[j], acc[i][j], 0, 0, 0);
    __syncthreads();
  }

  const int mB = m0 + wr * 64 + lg * 4;   // + i*16 + r
  const int nB = n0 + wc * 64 + l15;      // + j*16
  if constexpr (MODE == 0) {
    bf16* o = reinterpret_cast<bf16*>(out0);
    constexpr float SC = 0.125f * 1.44269504089f;  // DH^-0.5 * log2(e)
#pragma unroll
    for (int i = 0; i < 4; ++i)
#pragma unroll
      for (int j = 0; j < 4; ++j)
#pragma unroll
        for (int r = 0; r < 4; ++r)
          o[(size_t)(mB + i * 16 + r) * N + nB + j * 16] = (bf16)(acc[i][j][r] * SC);
  } else if constexpr (MODE == 2) {
    float* o = reinterpret_cast<float*>(out0);
#pragma unroll
    for (int j = 0; j < 4; ++j) {
      float bj = bias[nB + j * 16];
#pragma unroll
      for (int i = 0; i < 4; ++i)
#pragma unroll
        for (int r = 0; r < 4; ++r)
          o[(size_t)(mB + i * 16 + r) * N + nB + j * 16] = acc[i][j][r] + bj;
    }
  } else {
    if (n0 < 1024) {  // K part: (B,NKV,DI) flat = m*1024 + n
      bf16* o = reinterpret_cast<bf16*>(out0);
#pragma unroll
      for (int i = 0; i < 4; ++i)
#pragma unroll
        for (int j = 0; j < 4; ++j)
#pragma unroll
          for (int r = 0; r < 4; ++r)
            o[(size_t)(mB + i * 16 + r) * 1024 + nB + j * 16] = (bf16)acc[i][j][r];
    } else {          // V part: transposed (B,DI,NKV) with in-64 column swizzle
      bf16* o = reinterpret_cast<bf16*>(out1);
#pragma unroll
      for (int i = 0; i < 4; ++i) {
        int m = mB + i * 16;            // global row = b*2048 + kv  (kv mult of 4)
        int bb_ = m >> 11, kv = m & 2047;
        int u = kv & 63;
        // c = k2*32 + lg*8 + j2*4 + j1  from  kv = k2*32 + j2*16 + lg*4 + j1
        int c = (u & 32) | ((u & 12) << 1) | ((u & 16) >> 2) | (u & 3);
        int col = (kv & ~63) | c;
#pragma unroll
        for (int j = 0; j < 4; ++j) {
          int nv = nB + j * 16 - 1024;  // d index within DI
          bf16x4 pk;
          pk[0] = (bf16)acc[i][j][0]; pk[1] = (bf16)acc[i][j][1];
          pk[2] = (bf16)acc[i][j][2]; pk[3] = (bf16)acc[i][j][3];
          *reinterpret_cast<bf16x4*>(o + ((size_t)(bb_ << 10) + nv) * 2048 + col) = pk;
        }
      }
    }
  }
}

// ---------------- Flash attention v3: 16 q/wave, latency-oriented ----------------
// S^T = mfma(K, Q): lane holds S[q = lane&15][kv = ni*16 + lg*4 + r]  (exp2-domain logits).
// P stays in registers; V^T pre-swizzled so PV's B fragments are plain 16B loads.
__global__ __launch_bounds__(256, 4) void attn_kernel(const bf16* __restrict__ qp,
    const bf16* __restrict__ kk, const bf16* __restrict__ vTp, bf16* __restrict__ out) {
  // XCD swizzle: the 16 q-tile blocks of one (b,h) land on one XCD (assumes id%8 round-robin)
  const int p = blockIdx.x;
  const int L = (p & 7) * 128 + (p >> 3);
  const int bh = L >> 4, qt = L & 15;
  const int b = bh >> 4, h = bh & 15;
  const int tid = threadIdx.x;
  const int lane = tid & 63, w = tid >> 6;
  const int l15 = lane & 15, lg = lane >> 4;
  const int q0 = qt * 64 + w * 16;

  const bf16* Qb = qp + (size_t)(b * NQ + q0) * DI + h * DH;
  const bf16* Kb = kk + (size_t)b * NKV * DI + h * DH;
  const bf16* Vb = vTp + (size_t)(b * DI + h * DH) * NKV;

  bf16x8 qf[2];
#pragma unroll
  for (int ks = 0; ks < 2; ++ks)
    qf[ks] = *reinterpret_cast<const bf16x8*>(Qb + (size_t)l15 * DI + ks * 32 + lg * 8);

  f32x4 o[4] = {};
  float mrun = -1e30f, lrun = 0.0f;

  bf16x8 kf[4][2];
#pragma unroll
  for (int ni = 0; ni < 4; ++ni)
#pragma unroll
    for (int ks = 0; ks < 2; ++ks)
      kf[ni][ks] = *reinterpret_cast<const bf16x8*>(Kb + (size_t)(ni * 16 + l15) * DI + ks * 32 + lg * 8);

#pragma unroll 1
  for (int kv0 = 0; kv0 < NKV; kv0 += 64) {
    // V tile, first half — issue early, used ~500 cycles later
    bf16x8 vf0[4], vf1[4];
#pragma unroll
    for (int dt = 0; dt < 4; ++dt)
      vf0[dt] = *reinterpret_cast<const bf16x8*>(Vb + (size_t)(dt * 16 + l15) * NKV + kv0 + lg * 8);

    // QK^T (swapped operands)
    f32x4 s[4] = {};
#pragma unroll
    for (int ni = 0; ni < 4; ++ni)
#pragma unroll
      for (int ks = 0; ks < 2; ++ks)
        s[ni] = __builtin_amdgcn_mfma_f32_16x16x32_bf16(kf[ni][ks], qf[ks], s[ni], 0, 0, 0);

    // prefetch next K tile into the SAME registers (WAR reuse; softmax+PV hides latency)
    const int kvp = (kv0 + 64 < NKV) ? kv0 + 64 : 0;
#pragma unroll
    for (int ni = 0; ni < 4; ++ni)
#pragma unroll
      for (int ks = 0; ks < 2; ++ks)
        kf[ni][ks] = *reinterpret_cast<const bf16x8*>(Kb + (size_t)(kvp + ni * 16 + l15) * DI + ks * 32 + lg * 8);

    // V tile, second half
#pragma unroll
    for (int dt = 0; dt < 4; ++dt)
      vf1[dt] = *reinterpret_cast<const bf16x8*>(Vb + (size_t)(dt * 16 + l15) * NKV + kv0 + 32 + lg * 8);

    // ---- softmax (per q = l15; exp2 domain) ----
    float pm;
    {
      float m0_ = fmaxf(fmaxf(s[0][0], s[0][1]), fmaxf(s[0][2], s[0][3]));
      float m1_ = fmaxf(fmaxf(s[1][0], s[1][1]), fmaxf(s[1][2], s[1][3]));
      float m2_ = fmaxf(fmaxf(s[2][0], s[2][1]), fmaxf(s[2][2], s[2][3]));
      float m3_ = fmaxf(fmaxf(s[3][0], s[3][1]), fmaxf(s[3][2], s[3][3]));
      pm = fmaxf(fmaxf(m0_, m1_), fmaxf(m2_, m3_));
    }
    pm = fmaxf(pm, __shfl_xor(pm, 16));
    pm = fmaxf(pm, __shfl_xor(pm, 32));

    const bool noresc = __all(pm <= mrun);   // exact: corr == 1 when no new max
    const float mnew = noresc ? mrun : fmaxf(mrun, pm);

    float rsn[4];
#pragma unroll
    for (int ni = 0; ni < 4; ++ni) {
#pragma unroll
      for (int r = 0; r < 4; ++r)
        s[ni][r] = __builtin_amdgcn_exp2f(s[ni][r] - mnew);
      rsn[ni] = (s[ni][0] + s[ni][1]) + (s[ni][2] + s[ni][3]);
    }
    float rs = (rsn[0] + rsn[1]) + (rsn[2] + rsn[3]);
    rs += __shfl_xor(rs, 16);
    rs += __shfl_xor(rs, 32);

    if (noresc) {
      lrun += rs;
    } else {
      float corr = __builtin_amdgcn_exp2f(mrun - mnew);
      lrun = lrun * corr + rs;
      mrun = mnew;
      float c0 = __shfl(corr, lg * 4 + 0);
      float c1 = __shfl(corr, lg * 4 + 1);
      float c2 = __shfl(corr, lg * 4 + 2);
      float c3 = __shfl(corr, lg * 4 + 3);
#pragma unroll
      for (int dt = 0; dt < 4; ++dt) {
        o[dt][0] *= c0; o[dt][1] *= c1; o[dt][2] *= c2; o[dt][3] *= c3;
      }
    }

    // ---- pack P (register-only) and PV ----
    bf16x8 pa0, pa1;
#pragma unroll
    for (int jj = 0; jj < 4; ++jj) {
      pa0[jj]     = (bf16)s[0][jj];
      pa0[4 + jj] = (bf16)s[1][jj];
      pa1[jj]     = (bf16)s[2][jj];
      pa1[4 + jj] = (bf16)s[3][jj];
    }
#pragma unroll
    for (int dt = 0; dt < 4; ++dt)
      o[dt] = __builtin_amdgcn_mfma_f32_16x16x32_bf16(pa0, vf0[dt], o[dt], 0, 0, 0);
#pragma unroll
    for (int dt = 0; dt < 4; ++dt)
      o[dt] = __builtin_amdgcn_mfma_f32_16x16x32_bf16(pa1, vf1[dt], o[dt], 0, 0, 0);
  }

  const float inv = 1.0f / lrun;             // per q = l15
  const float iv0 = __shfl(inv, lg * 4 + 0);
  const float iv1 = __shfl(inv, lg * 4 + 1);
  const float iv2 = __shfl(inv, lg * 4 + 2);
  const float iv3 = __shfl(inv, lg * 4 + 3);

  bf16* Ob = out + (size_t)(b * NQ + q0) * DI + h * DH;
#pragma unroll
  for (int dt = 0; dt < 4; ++dt) {
    Ob[(size_t)(lg * 4 + 0) * DI + dt * 16 + l15] = (bf16)(o[dt][0] * iv0);
    Ob[(size_t)(lg * 4 + 1) * DI + dt * 16 + l15] = (bf16)(o[dt][1] * iv1);
    Ob[(size_t)(lg * 4 + 2) * DI + dt * 16 + l15] = (bf16)(o[dt][2] * iv2);
    Ob[(size_t)(lg * 4 + 3) * DI + dt * 16 + l15] = (bf16)(o[dt][3] * iv3);
  }
}

// ---------------- launch ----------------
extern "C" void kernel_launch(void* const* d_in, const int* in_sizes, int n_in,
                              void* d_out, int out_size, void* d_ws, size_t ws_size,
                              hipStream_t stream) {
  const float* q     = (const float*)d_in[0];
  const float* ctx   = (const float*)d_in[1];
  const float* Wq    = (const float*)d_in[2];
  const float* Wkv   = (const float*)d_in[3];
  const float* Wproj = (const float*)d_in[4];
  const float* bproj = (const float*)d_in[5];
  const float* qg    = (const float*)d_in[6];
  const float* qb    = (const float*)d_in[7];
  const float* cg    = (const float*)d_in[8];
  const float* cb    = (const float*)d_in[9];

  char* ws = (char*)d_ws;
  bf16* qn    = (bf16*)(ws);                       // 8 MB  (4096x1024)
  bf16* cn    = (bf16*)(ws + ( 8ull << 20));       // 16 MB (8192x1024)
  bf16* Wq_b  = (bf16*)(ws + (24ull << 20));       // 2 MB
  bf16* Wkv_b = (bf16*)(ws + (26ull << 20));       // 4 MB
  bf16* Wp_b  = (bf16*)(ws + (30ull << 20));       // 2 MB
  bf16* qpb   = (bf16*)(ws + (32ull << 20));       // 8 MB  (4096x1024)
  bf16* kbuf  = (bf16*)(ws + (40ull << 20));       // 16 MB (B,NKV,DI)
  bf16* vT    = (bf16*)(ws + (56ull << 20));       // 16 MB (B,DI,NKV) swizzled
  bf16* aout  = (bf16*)(ws + (72ull << 20));       // 8 MB  (4096x1024)

  cvt_kernel<<<1024, 256, 0, stream>>>(Wq,    Wq_b,  (1024 * 1024) / 4);
  cvt_kernel<<<2048, 256, 0, stream>>>(Wkv,   Wkv_b, (2048 * 1024) / 4);
  cvt_kernel<<<1024, 256, 0, stream>>>(Wproj, Wp_b,  (1024 * 1024) / 4);
  ln_kernel<<<4096, 256, 0, stream>>>(q,   qg, qb, qn);
  ln_kernel<<<8192, 256, 0, stream>>>(ctx, cg, cb, cn);

  gemm_bt<0><<<256,  256, 0, stream>>>(qn,   Wq_b,  qpb,  nullptr, nullptr, 4096, 1024);
  gemm_bt<1><<<1024, 256, 0, stream>>>(cn,   Wkv_b, kbuf, vT,      nullptr, 8192, 2048);

  attn_kernel<<<1024, 256, 0, stream>>>(qpb, kbuf, vT, aout);

  gemm_bt<2><<<256,  256, 0, stream>>>(aout, Wp_b,  d_out, nullptr, bproj, 4096, 1024);
}

// Round 5
// 190.727 us; speedup vs baseline: 1.8570x; 1.8570x over previous
//
#include <hip/hip_runtime.h>
#include <hip/hip_bf16.h>
#include <stdint.h>

#define B_N 4
#define NQ 1024
#define NKV 2048
#define DI 1024
#define H 16
#define DH 64

using bf16 = __bf16;
typedef bf16 bf16x8 __attribute__((ext_vector_type(8)));
typedef bf16 bf16x4 __attribute__((ext_vector_type(4)));
typedef float f32x4 __attribute__((ext_vector_type(4)));

typedef const __attribute__((address_space(1))) void* gptr_t;
typedef __attribute__((address_space(3))) void* sptr_t;

// ---------------- f32 -> bf16 convert ----------------
__global__ __launch_bounds__(256) void cvt_kernel(const float* __restrict__ in,
                                                  bf16* __restrict__ out, int n4) {
  int i = blockIdx.x * blockDim.x + threadIdx.x;
  if (i < n4) {
    float4 v = reinterpret_cast<const float4*>(in)[i];
    bf16x4 o;
    o[0] = (bf16)v.x; o[1] = (bf16)v.y; o[2] = (bf16)v.z; o[3] = (bf16)v.w;
    reinterpret_cast<bf16x4*>(out)[i] = o;
  }
}

// ---------------- LayerNorm (rows of 1024 f32) -> bf16 ----------------
__global__ __launch_bounds__(256) void ln_kernel(const float* __restrict__ x,
    const float* __restrict__ gamma, const float* __restrict__ beta,
    bf16* __restrict__ out) {
  int row = blockIdx.x;
  int t = threadIdx.x;
  const float4 v = reinterpret_cast<const float4*>(x + (size_t)row * 1024)[t];
  float s = v.x + v.y + v.z + v.w;
  float s2 = v.x*v.x + v.y*v.y + v.z*v.z + v.w*v.w;
#pragma unroll
  for (int m = 1; m < 64; m <<= 1) { s += __shfl_xor(s, m); s2 += __shfl_xor(s2, m); }
  __shared__ float red[8];
  int wid = t >> 6;
  if ((t & 63) == 0) { red[wid] = s; red[wid + 4] = s2; }
  __syncthreads();
  float ts  = red[0] + red[1] + red[2] + red[3];
  float ts2 = red[4] + red[5] + red[6] + red[7];
  float mean = ts * (1.0f / 1024.0f);
  float var  = ts2 * (1.0f / 1024.0f) - mean * mean;
  float rstd = rsqrtf(var + 1e-5f);
  float4 g  = reinterpret_cast<const float4*>(gamma)[t];
  float4 bb = reinterpret_cast<const float4*>(beta)[t];
  bf16x4 o;
  o[0] = (bf16)((v.x - mean) * rstd * g.x + bb.x);
  o[1] = (bf16)((v.y - mean) * rstd * g.y + bb.y);
  o[2] = (bf16)((v.z - mean) * rstd * g.z + bb.z);
  o[3] = (bf16)((v.w - mean) * rstd * g.w + bb.w);
  reinterpret_cast<bf16x4*>(out + (size_t)row * 1024)[t] = o;
}

// ---------------- GEMM: C[m,n] = sum_k A[m,k]*Bm[n,k]  (A: MxK, Bm: NxK, K=1024) ----
// MODE 0: bf16 out, * (0.125*log2e) (qp, exp2-domain logits)
// MODE 1: kv split -> out0 = K (B,NKV,DI) bf16, out1 = V^T permuted (B,DI,NKV) bf16
// MODE 2: f32 out + bias (proj)
template<int MODE>
__global__ __launch_bounds__(256) void gemm_bt(const bf16* __restrict__ A,
    const bf16* __restrict__ Bm, void* __restrict__ out0, void* __restrict__ out1,
    const float* __restrict__ bias, int M, int N) {
  constexpr int K = 1024;
  __shared__ bf16 lA[128 * 32];
  __shared__ bf16 lB[128 * 32];
  const int nbn = N >> 7;
  const int bm = blockIdx.x / nbn, bn = blockIdx.x - bm * nbn;
  const int m0 = bm << 7, n0 = bn << 7;
  const int tid = threadIdx.x;
  const int lane = tid & 63, wid = tid >> 6;
  const int wr = wid >> 1, wc = wid & 1;
  const int l15 = lane & 15, lg = lane >> 4;

  f32x4 acc[4][4] = {};

  const int c0 = tid, c1 = tid + 256;
  const bf16* gA0 = A  + (size_t)(m0 + (c0 >> 2)) * K + ((c0 & 3) << 3);
  const bf16* gA1 = A  + (size_t)(m0 + (c1 >> 2)) * K + ((c1 & 3) << 3);
  const bf16* gB0 = Bm + (size_t)(n0 + (c0 >> 2)) * K + ((c0 & 3) << 3);
  const bf16* gB1 = Bm + (size_t)(n0 + (c1 >> 2)) * K + ((c1 & 3) << 3);

  for (int k0 = 0; k0 < K; k0 += 32) {
    __builtin_amdgcn_global_load_lds((gptr_t)(gA0 + k0), (sptr_t)(lA + c0 * 8), 16, 0, 0);
    __builtin_amdgcn_global_load_lds((gptr_t)(gA1 + k0), (sptr_t)(lA + c1 * 8), 16, 0, 0);
    __builtin_amdgcn_global_load_lds((gptr_t)(gB0 + k0), (sptr_t)(lB + c0 * 8), 16, 0, 0);
    __builtin_amdgcn_global_load_lds((gptr_t)(gB1 + k0), (sptr_t)(lB + c1 * 8), 16, 0, 0);
    __syncthreads();
    bf16x8 af[4], bfr[4];
#pragma unroll
    for (int i = 0; i < 4; ++i) {
      af[i]  = *reinterpret_cast<const bf16x8*>(lA + (wr * 64 + i * 16 + l15) * 32 + lg * 8);
      bfr[i] = *reinterpret_cast<const bf16x8*>(lB + (wc * 64 + i * 16 + l15) * 32 + lg * 8);
    }
#pragma unroll
    for (int i = 0; i < 4; ++i)
#pragma unroll
      for (int j = 0; j < 4; ++j)
        acc[i][j] = __builtin_amdgcn_mfma_f32_16x16x32_bf16(af[i], bfr[j], acc[i][j], 0, 0, 0);
    __syncthreads();
  }

  const int mB = m0 + wr * 64 + lg * 4;   // + i*16 + r
  const int nB = n0 + wc * 64 + l15;      // + j*16
  if constexpr (MODE == 0) {
    bf16* o = reinterpret_cast<bf16*>(out0);
    constexpr float SC = 0.125f * 1.44269504089f;  // DH^-0.5 * log2(e)
#pragma unroll
    for (int i = 0; i < 4; ++i)
#pragma unroll
      for (int j = 0; j < 4; ++j)
#pragma unroll
        for (int r = 0; r < 4; ++r)
          o[(size_t)(mB + i * 16 + r) * N + nB + j * 16] = (bf16)(acc[i][j][r] * SC);
  } else if constexpr (MODE == 2) {
    float* o = reinterpret_cast<float*>(out0);
#pragma unroll
    for (int j = 0; j < 4; ++j) {
      float bj = bias[nB + j * 16];
#pragma unroll
      for (int i = 0; i < 4; ++i)
#pragma unroll
        for (int r = 0; r < 4; ++r)
          o[(size_t)(mB + i * 16 + r) * N + nB + j * 16] = acc[i][j][r] + bj;
    }
  } else {
    if (n0 < 1024) {  // K part: (B,NKV,DI) flat = m*1024 + n
      bf16* o = reinterpret_cast<bf16*>(out0);
#pragma unroll
      for (int i = 0; i < 4; ++i)
#pragma unroll
        for (int j = 0; j < 4; ++j)
#pragma unroll
          for (int r = 0; r < 4; ++r)
            o[(size_t)(mB + i * 16 + r) * 1024 + nB + j * 16] = (bf16)acc[i][j][r];
    } else {          // V part: transposed (B,DI,NKV) with in-64 column swizzle
      bf16* o = reinterpret_cast<bf16*>(out1);
#pragma unroll
      for (int i = 0; i < 4; ++i) {
        int m = mB + i * 16;            // global row = b*2048 + kv  (kv mult of 4)
        int bb_ = m >> 11, kv = m & 2047;
        int u = kv & 63;
        // c = k2*32 + lg*8 + j2*4 + j1  from  kv = k2*32 + j2*16 + lg*4 + j1
        int c = (u & 32) | ((u & 12) << 1) | ((u & 16) >> 2) | (u & 3);
        int col = (kv & ~63) | c;
#pragma unroll
        for (int j = 0; j < 4; ++j) {
          int nv = nB + j * 16 - 1024;  // d index within DI
          bf16x4 pk;
          pk[0] = (bf16)acc[i][j][0]; pk[1] = (bf16)acc[i][j][1];
          pk[2] = (bf16)acc[i][j][2]; pk[3] = (bf16)acc[i][j][3];
          *reinterpret_cast<bf16x4*>(o + ((size_t)(bb_ << 10) + nv) * 2048 + col) = pk;
        }
      }
    }
  }
}

// ---------------- Flash attention v5: LDS-staged K/V, 4 waves x 32q ----------------
// S^T = mfma(K, Q): lane holds S[q = lane&15][kv = ni*16 + lg*4 + r] (exp2-domain logits).
// K/V tiles staged to LDS in fragment-slot-major order: 16B slot = frag*64 + lane,
// so each ds_read_b128 is a contiguous 1KB sweep and all reads share vaddr lane*16.
// Stage source addresses carry the inverse permutation (pre-swizzled-source, linear LDS).
__global__ __launch_bounds__(256) void attn_kernel(const bf16* __restrict__ qp,
    const bf16* __restrict__ kk, const bf16* __restrict__ vTp, bf16* __restrict__ out) {
  __shared__ bf16 smem[16384];   // [K dbuf 2x4096][V dbuf 2x4096]
  // XCD-aware bijective remap: 8 q-tiles of one (b,h) land on one XCD (pos%8 round-robin)
  const int pos = blockIdx.x;
  const int idx = pos >> 3;
  const int bh = ((idx >> 3) << 3) | (pos & 7);
  const int qt = idx & 7;
  const int b = bh >> 4, h = bh & 15;
  const int tid = threadIdx.x;
  const int lane = tid & 63, w = tid >> 6;
  const int l15 = lane & 15, lg = lane >> 4;

  const bf16* Qb = qp + (size_t)(b * NQ + qt * 128 + w * 32) * DI + h * DH;
  const bf16* Kb = kk + (size_t)b * NKV * DI + h * DH;
  const bf16* Vb = vTp + (size_t)(b * DI + h * DH) * NKV;

  // staging: thread t covers slots {t, t+256}; slot bits: [8:7]=ni, [6]=ks, [5:4]=lg, [3:0]=l15
  const int s0 = tid, s1 = tid + 256;
  const int r0 = ((s0 >> 7) << 4) | (s0 & 15), c0_ = (s0 >> 4) & 7;
  const int r1 = ((s1 >> 7) << 4) | (s1 & 15), c1_ = (s1 >> 4) & 7;
  const bf16* pK0 = Kb + (size_t)r0 * DI + c0_ * 8;   // + kv0*DI per tile
  const bf16* pK1 = Kb + (size_t)r1 * DI + c1_ * 8;
  const bf16* pV0 = Vb + (size_t)r0 * NKV + c0_ * 8;  // + kv0 per tile
  const bf16* pV1 = Vb + (size_t)r1 * NKV + c1_ * 8;

#define STAGE_KV(bufsel, kv)                                                                         \
  do {                                                                                               \
    __builtin_amdgcn_global_load_lds((gptr_t)(pK0 + (size_t)(kv) * DI),                              \
                                     (sptr_t)(smem + (bufsel) * 4096 + s0 * 8), 16, 0, 0);           \
    __builtin_amdgcn_global_load_lds((gptr_t)(pK1 + (size_t)(kv) * DI),                              \
                                     (sptr_t)(smem + (bufsel) * 4096 + s1 * 8), 16, 0, 0);           \
    __builtin_amdgcn_global_load_lds((gptr_t)(pV0 + (kv)),                                           \
                                     (sptr_t)(smem + 8192 + (bufsel) * 4096 + s0 * 8), 16, 0, 0);    \
    __builtin_amdgcn_global_load_lds((gptr_t)(pV1 + (kv)),                                           \
                                     (sptr_t)(smem + 8192 + (bufsel) * 4096 + s1 * 8), 16, 0, 0);    \
  } while (0)

  bf16x8 qf[2][2];
#pragma unroll
  for (int mi = 0; mi < 2; ++mi)
#pragma unroll
    for (int ks = 0; ks < 2; ++ks)
      qf[mi][ks] = *reinterpret_cast<const bf16x8*>(Qb + (size_t)(mi * 16 + l15) * DI + ks * 32 + lg * 8);

  f32x4 o[2][4] = {};
  float mrun[2] = {-1e30f, -1e30f};
  float lrun[2] = {0.0f, 0.0f};

  STAGE_KV(0, 0);
  __syncthreads();
  int cur = 0;

  for (int kv0 = 0; kv0 < NKV; kv0 += 64) {
    const bool notlast = (kv0 + 64 < NKV);
    if (notlast) STAGE_KV(cur ^ 1, kv0 + 64);   // overlaps with this tile's compute

    const bf16* Kl = smem + cur * 4096;
    const bf16* Vl = smem + 8192 + cur * 4096;
    bf16x8 kf[4][2], vf[4][2];
#pragma unroll
    for (int ni = 0; ni < 4; ++ni)
#pragma unroll
      for (int ks = 0; ks < 2; ++ks)
        kf[ni][ks] = *reinterpret_cast<const bf16x8*>(Kl + ((ni * 2 + ks) * 64 + lane) * 8);
#pragma unroll
    for (int dt = 0; dt < 4; ++dt)
#pragma unroll
      for (int k2 = 0; k2 < 2; ++k2)
        vf[dt][k2] = *reinterpret_cast<const bf16x8*>(Vl + ((dt * 2 + k2) * 64 + lane) * 8);

    // QK^T (swapped operands)
    f32x4 s[2][4] = {};
#pragma unroll
    for (int mi = 0; mi < 2; ++mi)
#pragma unroll
      for (int ni = 0; ni < 4; ++ni)
#pragma unroll
        for (int ks = 0; ks < 2; ++ks)
          s[mi][ni] = __builtin_amdgcn_mfma_f32_16x16x32_bf16(kf[ni][ks], qf[mi][ks], s[mi][ni], 0, 0, 0);

    // softmax + PV per q-fragment (two independent chains)
#pragma unroll
    for (int mi = 0; mi < 2; ++mi) {
      float pm;
      {
        float m0_ = fmaxf(fmaxf(s[mi][0][0], s[mi][0][1]), fmaxf(s[mi][0][2], s[mi][0][3]));
        float m1_ = fmaxf(fmaxf(s[mi][1][0], s[mi][1][1]), fmaxf(s[mi][1][2], s[mi][1][3]));
        float m2_ = fmaxf(fmaxf(s[mi][2][0], s[mi][2][1]), fmaxf(s[mi][2][2], s[mi][2][3]));
        float m3_ = fmaxf(fmaxf(s[mi][3][0], s[mi][3][1]), fmaxf(s[mi][3][2], s[mi][3][3]));
        pm = fmaxf(fmaxf(m0_, m1_), fmaxf(m2_, m3_));
      }
      pm = fmaxf(pm, __shfl_xor(pm, 16));
      pm = fmaxf(pm, __shfl_xor(pm, 32));

      const bool noresc = __all(pm <= mrun[mi]);   // exact: corr == 1 when no new max
      const float mnew = noresc ? mrun[mi] : fmaxf(mrun[mi], pm);

      float rsn[4];
#pragma unroll
      for (int ni = 0; ni < 4; ++ni) {
#pragma unroll
        for (int r = 0; r < 4; ++r)
          s[mi][ni][r] = __builtin_amdgcn_exp2f(s[mi][ni][r] - mnew);
        rsn[ni] = (s[mi][ni][0] + s[mi][ni][1]) + (s[mi][ni][2] + s[mi][ni][3]);
      }
      float rs = (rsn[0] + rsn[1]) + (rsn[2] + rsn[3]);
      rs += __shfl_xor(rs, 16);
      rs += __shfl_xor(rs, 32);

      if (noresc) {
        lrun[mi] += rs;
      } else {
        float corr = __builtin_amdgcn_exp2f(mrun[mi] - mnew);
        lrun[mi] = lrun[mi] * corr + rs;
        mrun[mi] = mnew;
        float c0 = __shfl(corr, lg * 4 + 0);
        float c1 = __shfl(corr, lg * 4 + 1);
        float c2 = __shfl(corr, lg * 4 + 2);
        float c3 = __shfl(corr, lg * 4 + 3);
#pragma unroll
        for (int dt = 0; dt < 4; ++dt) {
          o[mi][dt][0] *= c0; o[mi][dt][1] *= c1; o[mi][dt][2] *= c2; o[mi][dt][3] *= c3;
        }
      }

      bf16x8 pa0, pa1;
#pragma unroll
      for (int jj = 0; jj < 4; ++jj) {
        pa0[jj]     = (bf16)s[mi][0][jj];
        pa0[4 + jj] = (bf16)s[mi][1][jj];
        pa1[jj]     = (bf16)s[mi][2][jj];
        pa1[4 + jj] = (bf16)s[mi][3][jj];
      }
#pragma unroll
      for (int dt = 0; dt < 4; ++dt)
        o[mi][dt] = __builtin_amdgcn_mfma_f32_16x16x32_bf16(pa0, vf[dt][0], o[mi][dt], 0, 0, 0);
#pragma unroll
      for (int dt = 0; dt < 4; ++dt)
        o[mi][dt] = __builtin_amdgcn_mfma_f32_16x16x32_bf16(pa1, vf[dt][1], o[mi][dt], 0, 0, 0);
    }

    if (notlast) __syncthreads();   // drains this tile's prefetch (already overlapped)
    cur ^= 1;
  }
#undef STAGE_KV

#pragma unroll
  for (int mi = 0; mi < 2; ++mi) {
    const float inv = 1.0f / lrun[mi];           // valid for q = l15
    const float iv0 = __shfl(inv, lg * 4 + 0);
    const float iv1 = __shfl(inv, lg * 4 + 1);
    const float iv2 = __shfl(inv, lg * 4 + 2);
    const float iv3 = __shfl(inv, lg * 4 + 3);
    bf16* Ob = out + (size_t)(b * NQ + qt * 128 + w * 32 + mi * 16) * DI + h * DH;
#pragma unroll
    for (int dt = 0; dt < 4; ++dt) {
      Ob[(size_t)(lg * 4 + 0) * DI + dt * 16 + l15] = (bf16)(o[mi][dt][0] * iv0);
      Ob[(size_t)(lg * 4 + 1) * DI + dt * 16 + l15] = (bf16)(o[mi][dt][1] * iv1);
      Ob[(size_t)(lg * 4 + 2) * DI + dt * 16 + l15] = (bf16)(o[mi][dt][2] * iv2);
      Ob[(size_t)(lg * 4 + 3) * DI + dt * 16 + l15] = (bf16)(o[mi][dt][3] * iv3);
    }
  }
}

// ---------------- launch ----------------
extern "C" void kernel_launch(void* const* d_in, const int* in_sizes, int n_in,
                              void* d_out, int out_size, void* d_ws, size_t ws_size,
                              hipStream_t stream) {
  const float* q     = (const float*)d_in[0];
  const float* ctx   = (const float*)d_in[1];
  const float* Wq    = (const float*)d_in[2];
  const float* Wkv   = (const float*)d_in[3];
  const float* Wproj = (const float*)d_in[4];
  const float* bproj = (const float*)d_in[5];
  const float* qg    = (const float*)d_in[6];
  const float* qb    = (const float*)d_in[7];
  const float* cg    = (const float*)d_in[8];
  const float* cb    = (const float*)d_in[9];

  char* ws = (char*)d_ws;
  bf16* qn    = (bf16*)(ws);                       // 8 MB  (4096x1024)
  bf16* cn    = (bf16*)(ws + ( 8ull << 20));       // 16 MB (8192x1024)
  bf16* Wq_b  = (bf16*)(ws + (24ull << 20));       // 2 MB
  bf16* Wkv_b = (bf16*)(ws + (26ull << 20));       // 4 MB
  bf16* Wp_b  = (bf16*)(ws + (30ull << 20));       // 2 MB
  bf16* qpb   = (bf16*)(ws + (32ull << 20));       // 8 MB  (4096x1024)
  bf16* kbuf  = (bf16*)(ws + (40ull << 20));       // 16 MB (B,NKV,DI)
  bf16* vT    = (bf16*)(ws + (56ull << 20));       // 16 MB (B,DI,NKV) swizzled
  bf16* aout  = (bf16*)(ws + (72ull << 20));       // 8 MB  (4096x1024)

  cvt_kernel<<<1024, 256, 0, stream>>>(Wq,    Wq_b,  (1024 * 1024) / 4);
  cvt_kernel<<<2048, 256, 0, stream>>>(Wkv,   Wkv_b, (2048 * 1024) / 4);
  cvt_kernel<<<1024, 256, 0, stream>>>(Wproj, Wp_b,  (1024 * 1024) / 4);
  ln_kernel<<<4096, 256, 0, stream>>>(q,   qg, qb, qn);
  ln_kernel<<<8192, 256, 0, stream>>>(ctx, cg, cb, cn);

  gemm_bt<0><<<256,  256, 0, stream>>>(qn,   Wq_b,  qpb,  nullptr, nullptr, 4096, 1024);
  gemm_bt<1><<<1024, 256, 0, stream>>>(cn,   Wkv_b, kbuf, vT,      nullptr, 8192, 2048);

  attn_kernel<<<512, 256, 0, stream>>>(qpb, kbuf, vT, aout);

  gemm_bt<2><<<256,  256, 0, stream>>>(aout, Wp_b,  d_out, nullptr, bproj, 4096, 1024);
}

// Round 6
// 173.026 us; speedup vs baseline: 2.0470x; 1.1023x over previous
//
#include <hip/hip_runtime.h>
#include <hip/hip_bf16.h>
#include <stdint.h>

#define B_N 4
#define NQ 1024
#define NKV 2048
#define DI 1024
#define H 16
#define DH 64

using bf16 = __bf16;
typedef bf16 bf16x8 __attribute__((ext_vector_type(8)));
typedef bf16 bf16x4 __attribute__((ext_vector_type(4)));
typedef float f32x4 __attribute__((ext_vector_type(4)));

typedef const __attribute__((address_space(1))) void* gptr_t;
typedef __attribute__((address_space(3))) void* sptr_t;

// ---------------- f32 -> bf16 convert ----------------
__global__ __launch_bounds__(256) void cvt_kernel(const float* __restrict__ in,
                                                  bf16* __restrict__ out, int n4) {
  int i = blockIdx.x * blockDim.x + threadIdx.x;
  if (i < n4) {
    float4 v = reinterpret_cast<const float4*>(in)[i];
    bf16x4 o;
    o[0] = (bf16)v.x; o[1] = (bf16)v.y; o[2] = (bf16)v.z; o[3] = (bf16)v.w;
    reinterpret_cast<bf16x4*>(out)[i] = o;
  }
}

// ---------------- LayerNorm (rows of 1024 f32) -> bf16 ----------------
__global__ __launch_bounds__(256) void ln_kernel(const float* __restrict__ x,
    const float* __restrict__ gamma, const float* __restrict__ beta,
    bf16* __restrict__ out) {
  int row = blockIdx.x;
  int t = threadIdx.x;
  const float4 v = reinterpret_cast<const float4*>(x + (size_t)row * 1024)[t];
  float s = v.x + v.y + v.z + v.w;
  float s2 = v.x*v.x + v.y*v.y + v.z*v.z + v.w*v.w;
#pragma unroll
  for (int m = 1; m < 64; m <<= 1) { s += __shfl_xor(s, m); s2 += __shfl_xor(s2, m); }
  __shared__ float red[8];
  int wid = t >> 6;
  if ((t & 63) == 0) { red[wid] = s; red[wid + 4] = s2; }
  __syncthreads();
  float ts  = red[0] + red[1] + red[2] + red[3];
  float ts2 = red[4] + red[5] + red[6] + red[7];
  float mean = ts * (1.0f / 1024.0f);
  float var  = ts2 * (1.0f / 1024.0f) - mean * mean;
  float rstd = rsqrtf(var + 1e-5f);
  float4 g  = reinterpret_cast<const float4*>(gamma)[t];
  float4 bb = reinterpret_cast<const float4*>(beta)[t];
  bf16x4 o;
  o[0] = (bf16)((v.x - mean) * rstd * g.x + bb.x);
  o[1] = (bf16)((v.y - mean) * rstd * g.y + bb.y);
  o[2] = (bf16)((v.z - mean) * rstd * g.z + bb.z);
  o[3] = (bf16)((v.w - mean) * rstd * g.w + bb.w);
  reinterpret_cast<bf16x4*>(out + (size_t)row * 1024)[t] = o;
}

// ---------------- GEMM: C[m,n] = sum_k A[m,k]*Bm[n,k]  (A: MxK, Bm: NxK, K=1024) ----
// Tile: 128 x BN (BN = 128 or 64). 4 waves.
//   BN=128: wave grid 2x2, per-wave 64x64 (acc 4x4)
//   BN= 64: wave grid 4x1, per-wave 32x64 (acc 2x4)
// MODE 0: bf16 out, * (0.125*log2e) (qp, exp2-domain logits)
// MODE 1: kv split -> out0 = K (B,NKV,DI) bf16, out1 = V^T permuted (B,DI,NKV) bf16
// MODE 2: f32 out + bias (proj)
template<int MODE, int BN>
__global__ __launch_bounds__(256) void gemm_bt(const bf16* __restrict__ A,
    const bf16* __restrict__ Bm, void* __restrict__ out0, void* __restrict__ out1,
    const float* __restrict__ bias, int M, int N) {
  constexpr int K = 1024;
  constexpr int MI = (BN == 128) ? 4 : 2;
  __shared__ bf16 lA[128 * 32];
  __shared__ bf16 lB[BN * 32];
  const int nbn = N / BN;
  const int bm = blockIdx.x / nbn, bn = blockIdx.x - bm * nbn;
  const int m0 = bm << 7, n0 = bn * BN;
  const int tid = threadIdx.x;
  const int lane = tid & 63, wid = tid >> 6;
  const int rowb = (BN == 128) ? ((wid >> 1) * 64) : (wid * 32);
  const int colb = (BN == 128) ? ((wid & 1) * 64) : 0;
  const int l15 = lane & 15, lg = lane >> 4;

  f32x4 acc[MI][4] = {};

  const int c0 = tid, c1 = tid + 256;
  const bf16* gA0 = A  + (size_t)(m0 + (c0 >> 2)) * K + ((c0 & 3) << 3);
  const bf16* gA1 = A  + (size_t)(m0 + (c1 >> 2)) * K + ((c1 & 3) << 3);
  const bf16* gB0 = Bm + (size_t)(n0 + (c0 >> 2)) * K + ((c0 & 3) << 3);
  const bf16* gB1 = Bm + (size_t)(n0 + (c1 >> 2)) * K + ((c1 & 3) << 3);

  for (int k0 = 0; k0 < K; k0 += 32) {
    __builtin_amdgcn_global_load_lds((gptr_t)(gA0 + k0), (sptr_t)(lA + c0 * 8), 16, 0, 0);
    __builtin_amdgcn_global_load_lds((gptr_t)(gA1 + k0), (sptr_t)(lA + c1 * 8), 16, 0, 0);
    __builtin_amdgcn_global_load_lds((gptr_t)(gB0 + k0), (sptr_t)(lB + c0 * 8), 16, 0, 0);
    if constexpr (BN == 128)
      __builtin_amdgcn_global_load_lds((gptr_t)(gB1 + k0), (sptr_t)(lB + c1 * 8), 16, 0, 0);
    __syncthreads();
    bf16x8 af[MI], bfr[4];
#pragma unroll
    for (int i = 0; i < MI; ++i)
      af[i]  = *reinterpret_cast<const bf16x8*>(lA + (rowb + i * 16 + l15) * 32 + lg * 8);
#pragma unroll
    for (int j = 0; j < 4; ++j)
      bfr[j] = *reinterpret_cast<const bf16x8*>(lB + (colb + j * 16 + l15) * 32 + lg * 8);
#pragma unroll
    for (int i = 0; i < MI; ++i)
#pragma unroll
      for (int j = 0; j < 4; ++j)
        acc[i][j] = __builtin_amdgcn_mfma_f32_16x16x32_bf16(af[i], bfr[j], acc[i][j], 0, 0, 0);
    __syncthreads();
  }

  const int mB = m0 + rowb + lg * 4;      // + i*16 + r
  const int nB = n0 + colb + l15;         // + j*16
  if constexpr (MODE == 0) {
    bf16* o = reinterpret_cast<bf16*>(out0);
    constexpr float SC = 0.125f * 1.44269504089f;  // DH^-0.5 * log2(e)
#pragma unroll
    for (int i = 0; i < MI; ++i)
#pragma unroll
      for (int j = 0; j < 4; ++j)
#pragma unroll
        for (int r = 0; r < 4; ++r)
          o[(size_t)(mB + i * 16 + r) * N + nB + j * 16] = (bf16)(acc[i][j][r] * SC);
  } else if constexpr (MODE == 2) {
    float* o = reinterpret_cast<float*>(out0);
#pragma unroll
    for (int j = 0; j < 4; ++j) {
      float bj = bias[nB + j * 16];
#pragma unroll
      for (int i = 0; i < MI; ++i)
#pragma unroll
        for (int r = 0; r < 4; ++r)
          o[(size_t)(mB + i * 16 + r) * N + nB + j * 16] = acc[i][j][r] + bj;
    }
  } else {
    if (n0 < 1024) {  // K part: (B,NKV,DI) flat = m*1024 + n
      bf16* o = reinterpret_cast<bf16*>(out0);
#pragma unroll
      for (int i = 0; i < MI; ++i)
#pragma unroll
        for (int j = 0; j < 4; ++j)
#pragma unroll
          for (int r = 0; r < 4; ++r)
            o[(size_t)(mB + i * 16 + r) * 1024 + nB + j * 16] = (bf16)acc[i][j][r];
    } else {          // V part: transposed (B,DI,NKV) with in-64 column swizzle
      bf16* o = reinterpret_cast<bf16*>(out1);
#pragma unroll
      for (int i = 0; i < MI; ++i) {
        int m = mB + i * 16;            // global row = b*2048 + kv  (kv mult of 4)
        int bb_ = m >> 11, kv = m & 2047;
        int u = kv & 63;
        // c = k2*32 + lg*8 + j2*4 + j1  from  kv = k2*32 + j2*16 + lg*4 + j1
        int c = (u & 32) | ((u & 12) << 1) | ((u & 16) >> 2) | (u & 3);
        int col = (kv & ~63) | c;
#pragma unroll
        for (int j = 0; j < 4; ++j) {
          int nv = nB + j * 16 - 1024;  // d index within DI
          bf16x4 pk;
          pk[0] = (bf16)acc[i][j][0]; pk[1] = (bf16)acc[i][j][1];
          pk[2] = (bf16)acc[i][j][2]; pk[3] = (bf16)acc[i][j][3];
          *reinterpret_cast<bf16x4*>(o + ((size_t)(bb_ << 10) + nv) * 2048 + col) = pk;
        }
      }
    }
  }
}

// ---------------- Flash attention v6: LDS-staged K/V, 8 waves x 16q ----------------
// S^T = mfma(K, Q): lane holds S[q = lane&15][kv = ni*16 + lg*4 + r] (exp2-domain logits).
// K/V tiles staged to LDS in fragment-slot-major order (16B slot = frag*64 + lane);
// stage source addresses carry the inverse permutation (pre-swizzled-source, linear LDS).
// Per-lane partial row-sum deferred to epilogue (corr is row-uniform -> linearity exact).
__global__ __launch_bounds__(512) void attn_kernel(const bf16* __restrict__ qp,
    const bf16* __restrict__ kk, const bf16* __restrict__ vTp, bf16* __restrict__ out) {
  __shared__ bf16 smem[16384];   // [K dbuf 2x4096][V dbuf 2x4096]
  // XCD-aware bijective remap: the 8 q-tiles of one (b,h) land on one XCD
  const int pos = blockIdx.x;
  const int idx = pos >> 3;
  const int bh = ((idx >> 3) << 3) | (pos & 7);
  const int qt = idx & 7;
  const int b = bh >> 4, h = bh & 15;
  const int tid = threadIdx.x;            // 0..511
  const int lane = tid & 63, w = tid >> 6;  // 8 waves
  const int l15 = lane & 15, lg = lane >> 4;

  const bf16* Qb = qp + (size_t)(b * NQ + qt * 128 + w * 16) * DI + h * DH;
  const bf16* Kb = kk + (size_t)b * NKV * DI + h * DH;
  const bf16* Vb = vTp + (size_t)(b * DI + h * DH) * NKV;

  // staging: thread t covers slot t (of 512); slot bits: [8:7]=ni, [6]=ks, [5:4]=lg, [3:0]=l15
  const int r0 = ((tid >> 7) << 4) | (tid & 15);
  const int c0_ = (tid >> 4) & 7;
  const bf16* pK0 = Kb + (size_t)r0 * DI + c0_ * 8;   // + kv0*DI per tile
  const bf16* pV0 = Vb + (size_t)r0 * NKV + c0_ * 8;  // + kv0 per tile

#define STAGE_KV(bufsel, kv)                                                                       \
  do {                                                                                             \
    __builtin_amdgcn_global_load_lds((gptr_t)(pK0 + (size_t)(kv) * DI),                            \
                                     (sptr_t)(smem + (bufsel) * 4096 + tid * 8), 16, 0, 0);        \
    __builtin_amdgcn_global_load_lds((gptr_t)(pV0 + (kv)),                                         \
                                     (sptr_t)(smem + 8192 + (bufsel) * 4096 + tid * 8), 16, 0, 0); \
  } while (0)

  bf16x8 qf[2];
#pragma unroll
  for (int ks = 0; ks < 2; ++ks)
    qf[ks] = *reinterpret_cast<const bf16x8*>(Qb + (size_t)l15 * DI + ks * 32 + lg * 8);

  f32x4 o[4] = {};
  float mrun = -1e30f;
  float lpart = 0.0f;    // per-lane partial row-sum (reduced across lg at epilogue)

  STAGE_KV(0, 0);
  __syncthreads();
  int cur = 0;

  for (int kv0 = 0; kv0 < NKV; kv0 += 64) {
    const bool notlast = (kv0 + 64 < NKV);
    if (notlast) STAGE_KV(cur ^ 1, kv0 + 64);   // overlaps with this tile's compute

    const bf16* Kl = smem + cur * 4096;
    const bf16* Vl = smem + 8192 + cur * 4096;
    bf16x8 kf[4][2], vf[4][2];
#pragma unroll
    for (int ni = 0; ni < 4; ++ni)
#pragma unroll
      for (int ks = 0; ks < 2; ++ks)
        kf[ni][ks] = *reinterpret_cast<const bf16x8*>(Kl + ((ni * 2 + ks) * 64 + lane) * 8);
#pragma unroll
    for (int dt = 0; dt < 4; ++dt)
#pragma unroll
      for (int k2 = 0; k2 < 2; ++k2)
        vf[dt][k2] = *reinterpret_cast<const bf16x8*>(Vl + ((dt * 2 + k2) * 64 + lane) * 8);

    // QK^T (swapped operands)
    f32x4 s[4] = {};
    __builtin_amdgcn_s_setprio(1);
#pragma unroll
    for (int ni = 0; ni < 4; ++ni)
#pragma unroll
      for (int ks = 0; ks < 2; ++ks)
        s[ni] = __builtin_amdgcn_mfma_f32_16x16x32_bf16(kf[ni][ks], qf[ks], s[ni], 0, 0, 0);
    __builtin_amdgcn_s_setprio(0);

    // ---- softmax (per q = l15; exp2 domain) ----
    float pm;
    {
      float m0_ = fmaxf(fmaxf(s[0][0], s[0][1]), fmaxf(s[0][2], s[0][3]));
      float m1_ = fmaxf(fmaxf(s[1][0], s[1][1]), fmaxf(s[1][2], s[1][3]));
      float m2_ = fmaxf(fmaxf(s[2][0], s[2][1]), fmaxf(s[2][2], s[2][3]));
      float m3_ = fmaxf(fmaxf(s[3][0], s[3][1]), fmaxf(s[3][2], s[3][3]));
      pm = fmaxf(fmaxf(m0_, m1_), fmaxf(m2_, m3_));
    }
    pm = fmaxf(pm, __shfl_xor(pm, 16));
    pm = fmaxf(pm, __shfl_xor(pm, 32));

    const bool noresc = __all(pm <= mrun);   // exact: corr == 1 when no new max
    const float mnew = noresc ? mrun : fmaxf(mrun, pm);

    float rsn[4];
#pragma unroll
    for (int ni = 0; ni < 4; ++ni) {
#pragma unroll
      for (int r = 0; r < 4; ++r)
        s[ni][r] = __builtin_amdgcn_exp2f(s[ni][r] - mnew);
      rsn[ni] = (s[ni][0] + s[ni][1]) + (s[ni][2] + s[ni][3]);
    }
    const float rs_local = (rsn[0] + rsn[1]) + (rsn[2] + rsn[3]);

    if (noresc) {
      lpart += rs_local;
    } else {
      float corr = __builtin_amdgcn_exp2f(mrun - mnew);
      lpart = lpart * corr + rs_local;
      mrun = mnew;
      float c0 = __shfl(corr, lg * 4 + 0);
      float c1 = __shfl(corr, lg * 4 + 1);
      float c2 = __shfl(corr, lg * 4 + 2);
      float c3 = __shfl(corr, lg * 4 + 3);
#pragma unroll
      for (int dt = 0; dt < 4; ++dt) {
        o[dt][0] *= c0; o[dt][1] *= c1; o[dt][2] *= c2; o[dt][3] *= c3;
      }
    }

    // ---- pack P (register-only) and PV ----
    bf16x8 pa0, pa1;
#pragma unroll
    for (int jj = 0; jj < 4; ++jj) {
      pa0[jj]     = (bf16)s[0][jj];
      pa0[4 + jj] = (bf16)s[1][jj];
      pa1[jj]     = (bf16)s[2][jj];
      pa1[4 + jj] = (bf16)s[3][jj];
    }
    __builtin_amdgcn_s_setprio(1);
#pragma unroll
    for (int dt = 0; dt < 4; ++dt)
      o[dt] = __builtin_amdgcn_mfma_f32_16x16x32_bf16(pa0, vf[dt][0], o[dt], 0, 0, 0);
#pragma unroll
    for (int dt = 0; dt < 4; ++dt)
      o[dt] = __builtin_amdgcn_mfma_f32_16x16x32_bf16(pa1, vf[dt][1], o[dt], 0, 0, 0);
    __builtin_amdgcn_s_setprio(0);

    if (notlast) __syncthreads();   // drains this tile's prefetch (already overlapped)
    cur ^= 1;
  }
#undef STAGE_KV

  // epilogue: reduce per-lane partials, normalize, store
  float lsum = lpart;
  lsum += __shfl_xor(lsum, 16);
  lsum += __shfl_xor(lsum, 32);
  const float inv = 1.0f / lsum;               // valid for q = l15
  const float iv0 = __shfl(inv, lg * 4 + 0);
  const float iv1 = __shfl(inv, lg * 4 + 1);
  const float iv2 = __shfl(inv, lg * 4 + 2);
  const float iv3 = __shfl(inv, lg * 4 + 3);

  bf16* Ob = out + (size_t)(b * NQ + qt * 128 + w * 16) * DI + h * DH;
#pragma unroll
  for (int dt = 0; dt < 4; ++dt) {
    Ob[(size_t)(lg * 4 + 0) * DI + dt * 16 + l15] = (bf16)(o[dt][0] * iv0);
    Ob[(size_t)(lg * 4 + 1) * DI + dt * 16 + l15] = (bf16)(o[dt][1] * iv1);
    Ob[(size_t)(lg * 4 + 2) * DI + dt * 16 + l15] = (bf16)(o[dt][2] * iv2);
    Ob[(size_t)(lg * 4 + 3) * DI + dt * 16 + l15] = (bf16)(o[dt][3] * iv3);
  }
}

// ---------------- launch ----------------
extern "C" void kernel_launch(void* const* d_in, const int* in_sizes, int n_in,
                              void* d_out, int out_size, void* d_ws, size_t ws_size,
                              hipStream_t stream) {
  const float* q     = (const float*)d_in[0];
  const float* ctx   = (const float*)d_in[1];
  const float* Wq    = (const float*)d_in[2];
  const float* Wkv   = (const float*)d_in[3];
  const float* Wproj = (const float*)d_in[4];
  const float* bproj = (const float*)d_in[5];
  const float* qg    = (const float*)d_in[6];
  const float* qb    = (const float*)d_in[7];
  const float* cg    = (const float*)d_in[8];
  const float* cb    = (const float*)d_in[9];

  char* ws = (char*)d_ws;
  bf16* qn    = (bf16*)(ws);                       // 8 MB  (4096x1024)
  bf16* cn    = (bf16*)(ws + ( 8ull << 20));       // 16 MB (8192x1024)
  bf16* Wq_b  = (bf16*)(ws + (24ull << 20));       // 2 MB
  bf16* Wkv_b = (bf16*)(ws + (26ull << 20));       // 4 MB
  bf16* Wp_b  = (bf16*)(ws + (30ull << 20));       // 2 MB
  bf16* qpb   = (bf16*)(ws + (32ull << 20));       // 8 MB  (4096x1024)
  bf16* kbuf  = (bf16*)(ws + (40ull << 20));       // 16 MB (B,NKV,DI)
  bf16* vT    = (bf16*)(ws + (56ull << 20));       // 16 MB (B,DI,NKV) swizzled
  bf16* aout  = (bf16*)(ws + (72ull << 20));       // 8 MB  (4096x1024)

  cvt_kernel<<<1024, 256, 0, stream>>>(Wq,    Wq_b,  (1024 * 1024) / 4);
  cvt_kernel<<<2048, 256, 0, stream>>>(Wkv,   Wkv_b, (2048 * 1024) / 4);
  cvt_kernel<<<1024, 256, 0, stream>>>(Wproj, Wp_b,  (1024 * 1024) / 4);
  ln_kernel<<<4096, 256, 0, stream>>>(q,   qg, qb, qn);
  ln_kernel<<<8192, 256, 0, stream>>>(ctx, cg, cb, cn);

  gemm_bt<0, 64><<<512,  256, 0, stream>>>(qn,   Wq_b,  qpb,  nullptr, nullptr, 4096, 1024);
  gemm_bt<1,128><<<1024, 256, 0, stream>>>(cn,   Wkv_b, kbuf, vT,      nullptr, 8192, 2048);

  attn_kernel<<<512, 512, 0, stream>>>(qpb, kbuf, vT, aout);

  gemm_bt<2, 64><<<512,  256, 0, stream>>>(aout, Wp_b,  d_out, nullptr, bproj, 4096, 1024);
}

// Round 7
// 163.810 us; speedup vs baseline: 2.1622x; 1.0563x over previous
//
#include <hip/hip_runtime.h>
#include <hip/hip_bf16.h>
#include <stdint.h>

#define B_N 4
#define NQ 1024
#define NKV 2048
#define DI 1024
#define H 16
#define DH 64

using bf16 = __bf16;
typedef bf16 bf16x8 __attribute__((ext_vector_type(8)));
typedef bf16 bf16x4 __attribute__((ext_vector_type(4)));
typedef float f32x4 __attribute__((ext_vector_type(4)));

typedef const __attribute__((address_space(1))) void* gptr_t;
typedef __attribute__((address_space(3))) void* sptr_t;

// ---------------- fused f32 -> bf16 convert of all three weights ----------------
// Wq: 256K float4 | Wkv: 512K float4 | Wproj: 256K float4  (total 1M float4)
__global__ __launch_bounds__(256) void cvt_all(const float* __restrict__ Wq,
    const float* __restrict__ Wkv, const float* __restrict__ Wproj,
    bf16* __restrict__ oq, bf16* __restrict__ okv, bf16* __restrict__ op) {
  int i = blockIdx.x * 256 + threadIdx.x;
  const float* src; bf16* dst; int j;
  if (i < 262144)      { src = Wq;    dst = oq;  j = i; }
  else if (i < 786432) { src = Wkv;   dst = okv; j = i - 262144; }
  else                 { src = Wproj; dst = op;  j = i - 786432; }
  float4 v = reinterpret_cast<const float4*>(src)[j];
  bf16x4 o;
  o[0] = (bf16)v.x; o[1] = (bf16)v.y; o[2] = (bf16)v.z; o[3] = (bf16)v.w;
  reinterpret_cast<bf16x4*>(dst)[j] = o;
}

// ---------------- fused LayerNorm (q rows then ctx rows) -> bf16 ----------------
__global__ __launch_bounds__(256) void ln_kernel(const float* __restrict__ q,
    const float* __restrict__ ctx,
    const float* __restrict__ qg, const float* __restrict__ qb,
    const float* __restrict__ cg, const float* __restrict__ cb,
    bf16* __restrict__ qn, bf16* __restrict__ cn) {
  int row = blockIdx.x;
  const float* x; const float* gamma; const float* beta; bf16* out; int r;
  if (row < 4096) { x = q;   gamma = qg; beta = qb; out = qn; r = row; }
  else            { x = ctx; gamma = cg; beta = cb; out = cn; r = row - 4096; }
  int t = threadIdx.x;
  const float4 v = reinterpret_cast<const float4*>(x + (size_t)r * 1024)[t];
  float s = v.x + v.y + v.z + v.w;
  float s2 = v.x*v.x + v.y*v.y + v.z*v.z + v.w*v.w;
#pragma unroll
  for (int m = 1; m < 64; m <<= 1) { s += __shfl_xor(s, m); s2 += __shfl_xor(s2, m); }
  __shared__ float red[8];
  int wid = t >> 6;
  if ((t & 63) == 0) { red[wid] = s; red[wid + 4] = s2; }
  __syncthreads();
  float ts  = red[0] + red[1] + red[2] + red[3];
  float ts2 = red[4] + red[5] + red[6] + red[7];
  float mean = ts * (1.0f / 1024.0f);
  float var  = ts2 * (1.0f / 1024.0f) - mean * mean;
  float rstd = rsqrtf(var + 1e-5f);
  float4 g  = reinterpret_cast<const float4*>(gamma)[t];
  float4 bb = reinterpret_cast<const float4*>(beta)[t];
  bf16x4 o;
  o[0] = (bf16)((v.x - mean) * rstd * g.x + bb.x);
  o[1] = (bf16)((v.y - mean) * rstd * g.y + bb.y);
  o[2] = (bf16)((v.z - mean) * rstd * g.z + bb.z);
  o[3] = (bf16)((v.w - mean) * rstd * g.w + bb.w);
  reinterpret_cast<bf16x4*>(out + (size_t)r * 1024)[t] = o;
}

// ---------------- GEMM: C[m,n] = sum_k A[m,k]*Bm[n,k]  (A: MxK, Bm: NxK, K=1024) ----
// Tile: 128 x BN, BK=64, 4 waves.
//   BN=128: wave grid 2x2, per-wave 64x64 (acc 4x4)
//   BN= 64: wave grid 4x1, per-wave 32x64 (acc 2x4)
// MODE 0: bf16 out, * (0.125*log2e) (qp, exp2-domain logits)
// MODE 1: kv split -> out0 = K (B,NKV,DI) bf16, out1 = V^T permuted (B,DI,NKV) bf16
// MODE 2: f32 out + bias (proj)
template<int MODE, int BN>
__global__ __launch_bounds__(256) void gemm_bt(const bf16* __restrict__ A,
    const bf16* __restrict__ Bm, void* __restrict__ out0, void* __restrict__ out1,
    const float* __restrict__ bias, int M, int N) {
  constexpr int K = 1024;
  constexpr int MI = (BN == 128) ? 4 : 2;
  constexpr int NBL = (BN == 128) ? 4 : 2;     // B staging loads/thread
  __shared__ bf16 lA[128 * 64];
  __shared__ bf16 lB[BN * 64];
  const int nbn = N / BN;
  const int bm = blockIdx.x / nbn, bn = blockIdx.x - bm * nbn;
  const int m0 = bm << 7, n0 = bn * BN;
  const int tid = threadIdx.x;
  const int lane = tid & 63, wid = tid >> 6;
  const int rowb = (BN == 128) ? ((wid >> 1) * 64) : (wid * 32);
  const int colb = (BN == 128) ? ((wid & 1) * 64) : 0;
  const int l15 = lane & 15, lg = lane >> 4;

  f32x4 acc[MI][4] = {};

  const bf16* gA[4]; const bf16* gB[NBL];
#pragma unroll
  for (int u = 0; u < 4; ++u) {
    int s = tid + u * 256;
    gA[u] = A + (size_t)(m0 + (s >> 3)) * K + ((s & 7) << 3);
  }
#pragma unroll
  for (int u = 0; u < NBL; ++u) {
    int s = tid + u * 256;
    gB[u] = Bm + (size_t)(n0 + (s >> 3)) * K + ((s & 7) << 3);
  }

  for (int k0 = 0; k0 < K; k0 += 64) {
#pragma unroll
    for (int u = 0; u < 4; ++u)
      __builtin_amdgcn_global_load_lds((gptr_t)(gA[u] + k0), (sptr_t)(lA + (tid + u * 256) * 8), 16, 0, 0);
#pragma unroll
    for (int u = 0; u < NBL; ++u)
      __builtin_amdgcn_global_load_lds((gptr_t)(gB[u] + k0), (sptr_t)(lB + (tid + u * 256) * 8), 16, 0, 0);
    __syncthreads();
#pragma unroll
    for (int ks2 = 0; ks2 < 2; ++ks2) {
      bf16x8 af[MI], bfr[4];
#pragma unroll
      for (int i = 0; i < MI; ++i)
        af[i]  = *reinterpret_cast<const bf16x8*>(lA + (rowb + i * 16 + l15) * 64 + ks2 * 32 + lg * 8);
#pragma unroll
      for (int j = 0; j < 4; ++j)
        bfr[j] = *reinterpret_cast<const bf16x8*>(lB + (colb + j * 16 + l15) * 64 + ks2 * 32 + lg * 8);
#pragma unroll
      for (int i = 0; i < MI; ++i)
#pragma unroll
        for (int j = 0; j < 4; ++j)
          acc[i][j] = __builtin_amdgcn_mfma_f32_16x16x32_bf16(af[i], bfr[j], acc[i][j], 0, 0, 0);
    }
    __syncthreads();
  }

  const int mB = m0 + rowb + lg * 4;      // + i*16 + r
  const int nB = n0 + colb + l15;         // + j*16
  if constexpr (MODE == 0) {
    bf16* o = reinterpret_cast<bf16*>(out0);
    constexpr float SC = 0.125f * 1.44269504089f;  // DH^-0.5 * log2(e)
#pragma unroll
    for (int i = 0; i < MI; ++i)
#pragma unroll
      for (int j = 0; j < 4; ++j)
#pragma unroll
        for (int r = 0; r < 4; ++r)
          o[(size_t)(mB + i * 16 + r) * N + nB + j * 16] = (bf16)(acc[i][j][r] * SC);
  } else if constexpr (MODE == 2) {
    float* o = reinterpret_cast<float*>(out0);
#pragma unroll
    for (int j = 0; j < 4; ++j) {
      float bj = bias[nB + j * 16];
#pragma unroll
      for (int i = 0; i < MI; ++i)
#pragma unroll
        for (int r = 0; r < 4; ++r)
          o[(size_t)(mB + i * 16 + r) * N + nB + j * 16] = acc[i][j][r] + bj;
    }
  } else {
    if (n0 < 1024) {  // K part: (B,NKV,DI) flat = m*1024 + n
      bf16* o = reinterpret_cast<bf16*>(out0);
#pragma unroll
      for (int i = 0; i < MI; ++i)
#pragma unroll
        for (int j = 0; j < 4; ++j)
#pragma unroll
          for (int r = 0; r < 4; ++r)
            o[(size_t)(mB + i * 16 + r) * 1024 + nB + j * 16] = (bf16)acc[i][j][r];
    } else {          // V part: transposed (B,DI,NKV) with in-64 column swizzle
      bf16* o = reinterpret_cast<bf16*>(out1);
#pragma unroll
      for (int i = 0; i < MI; ++i) {
        int m = mB + i * 16;            // global row = b*2048 + kv  (kv mult of 4)
        int bb_ = m >> 11, kv = m & 2047;
        int u = kv & 63;
        // c = k2*32 + lg*8 + j2*4 + j1  from  kv = k2*32 + j2*16 + lg*4 + j1
        int c = (u & 32) | ((u & 12) << 1) | ((u & 16) >> 2) | (u & 3);
        int col = (kv & ~63) | c;
#pragma unroll
        for (int j = 0; j < 4; ++j) {
          int nv = nB + j * 16 - 1024;  // d index within DI
          bf16x4 pk;
          pk[0] = (bf16)acc[i][j][0]; pk[1] = (bf16)acc[i][j][1];
          pk[2] = (bf16)acc[i][j][2]; pk[3] = (bf16)acc[i][j][3];
          *reinterpret_cast<bf16x4*>(o + ((size_t)(bb_ << 10) + nv) * 2048 + col) = pk;
        }
      }
    }
  }
}

// ---------------- Flash attention v7: LDS-staged K/V, KVBLK=128, 8 waves x 16q ----------------
// S^T = mfma(K, Q): lane holds S[q = lane&15][kv = ni*16 + lg*4 + r] (exp2-domain logits).
// K/V tiles staged to LDS in fragment-slot-major order (16B slot = frag*64 + lane);
// stage source addresses carry the inverse permutation (pre-swizzled-source, linear LDS).
// 128-kv tile = two 64-groups; the V in-64 column swizzle applies per group.
__global__ __launch_bounds__(512, 4) void attn_kernel(const bf16* __restrict__ qp,
    const bf16* __restrict__ kk, const bf16* __restrict__ vTp, bf16* __restrict__ out) {
  __shared__ bf16 smem[32768];   // [K dbuf 2x8192][V dbuf 2x8192]  (64 KB)
  // XCD-aware bijective remap: the 8 q-tiles of one (b,h) land on one XCD
  const int pos = blockIdx.x;
  const int idx = pos >> 3;
  const int bh = ((idx >> 3) << 3) | (pos & 7);
  const int qt = idx & 7;
  const int b = bh >> 4, h = bh & 15;
  const int tid = threadIdx.x;              // 0..511
  const int lane = tid & 63, w = tid >> 6;  // 8 waves
  const int l15 = lane & 15, lg = lane >> 4;

  const bf16* Qb = qp + (size_t)(b * NQ + qt * 128 + w * 16) * DI + h * DH;
  const bf16* Kb = kk + (size_t)b * NKV * DI + h * DH;
  const bf16* Vb = vTp + (size_t)(b * DI + h * DH) * NKV;

  // K slots (1024 x 16B): bits [9:7]=ni, [6]=ks, [5:4]=lg, [3:0]=l15
  // V slots (1024 x 16B): bits [9:8]=dt, [7:6]=k2, [5:4]=lg, [3:0]=l15
  const int sA = tid, sB = tid + 512;
  const int rKA = ((sA >> 7) << 4) | (sA & 15), cKA = ((sA >> 4) & 7) * 8;
  const int rKB = ((sB >> 7) << 4) | (sB & 15), cKB = ((sB >> 4) & 7) * 8;
  const int rVA = ((sA >> 8) << 4) | (sA & 15), cVA = ((sA >> 6) & 3) * 32 + ((sA >> 4) & 3) * 8;
  const int rVB = ((sB >> 8) << 4) | (sB & 15), cVB = ((sB >> 6) & 3) * 32 + ((sB >> 4) & 3) * 8;
  const bf16* pKA = Kb + (size_t)rKA * DI + cKA;   // + kv0*DI per tile
  const bf16* pKB = Kb + (size_t)rKB * DI + cKB;
  const bf16* pVA = Vb + (size_t)rVA * NKV + cVA;  // + kv0 per tile
  const bf16* pVB = Vb + (size_t)rVB * NKV + cVB;

#define STAGE_KV(bufsel, kv)                                                                        \
  do {                                                                                              \
    __builtin_amdgcn_global_load_lds((gptr_t)(pKA + (size_t)(kv) * DI),                             \
                                     (sptr_t)(smem + (bufsel) * 8192 + sA * 8), 16, 0, 0);          \
    __builtin_amdgcn_global_load_lds((gptr_t)(pKB + (size_t)(kv) * DI),                             \
                                     (sptr_t)(smem + (bufsel) * 8192 + sB * 8), 16, 0, 0);          \
    __builtin_amdgcn_global_load_lds((gptr_t)(pVA + (kv)),                                          \
                                     (sptr_t)(smem + 16384 + (bufsel) * 8192 + sA * 8), 16, 0, 0);  \
    __builtin_amdgcn_global_load_lds((gptr_t)(pVB + (kv)),                                          \
                                     (sptr_t)(smem + 16384 + (bufsel) * 8192 + sB * 8), 16, 0, 0);  \
  } while (0)

  bf16x8 qf[2];
#pragma unroll
  for (int ks = 0; ks < 2; ++ks)
    qf[ks] = *reinterpret_cast<const bf16x8*>(Qb + (size_t)l15 * DI + ks * 32 + lg * 8);

  f32x4 o[4] = {};
  float mrun = -1e30f;
  float lpart = 0.0f;    // per-lane partial row-sum (reduced across lg at epilogue)

  STAGE_KV(0, 0);
  __syncthreads();
  int cur = 0;

  for (int kv0 = 0; kv0 < NKV; kv0 += 128) {
    const bool notlast = (kv0 + 128 < NKV);
    if (notlast) STAGE_KV(cur ^ 1, kv0 + 128);   // issue early; drained by tile-end barrier

    const bf16* Kl = smem + cur * 8192;
    const bf16* Vl = smem + 16384 + cur * 8192;

    // ---- QK^T (swapped operands), two 64-kv groups ----
    f32x4 s[8] = {};
#pragma unroll
    for (int h2 = 0; h2 < 2; ++h2) {
      bf16x8 kf[4][2];
#pragma unroll
      for (int ni = 0; ni < 4; ++ni)
#pragma unroll
        for (int ks = 0; ks < 2; ++ks)
          kf[ni][ks] = *reinterpret_cast<const bf16x8*>(Kl + (((h2 * 4 + ni) * 2 + ks) * 64 + lane) * 8);
      __builtin_amdgcn_s_setprio(1);
#pragma unroll
      for (int ni = 0; ni < 4; ++ni)
#pragma unroll
        for (int ks = 0; ks < 2; ++ks)
          s[h2 * 4 + ni] = __builtin_amdgcn_mfma_f32_16x16x32_bf16(kf[ni][ks], qf[ks], s[h2 * 4 + ni], 0, 0, 0);
      __builtin_amdgcn_s_setprio(0);
    }

    // ---- softmax (per q = l15; exp2 domain) ----
    f32x4 mv = s[0];
#pragma unroll
    for (int i = 1; i < 8; ++i) {
      mv[0] = fmaxf(mv[0], s[i][0]); mv[1] = fmaxf(mv[1], s[i][1]);
      mv[2] = fmaxf(mv[2], s[i][2]); mv[3] = fmaxf(mv[3], s[i][3]);
    }
    float pm = fmaxf(fmaxf(mv[0], mv[1]), fmaxf(mv[2], mv[3]));
    pm = fmaxf(pm, __shfl_xor(pm, 16));
    pm = fmaxf(pm, __shfl_xor(pm, 32));

    const bool noresc = __all(pm <= mrun);   // exact: corr == 1 when no new max
    const float mnew = noresc ? mrun : fmaxf(mrun, pm);

    f32x4 sv = {};
#pragma unroll
    for (int i = 0; i < 8; ++i) {
#pragma unroll
      for (int r = 0; r < 4; ++r) {
        s[i][r] = __builtin_amdgcn_exp2f(s[i][r] - mnew);
        sv[r] += s[i][r];
      }
    }
    const float rs_local = (sv[0] + sv[1]) + (sv[2] + sv[3]);

    if (noresc) {
      lpart += rs_local;
    } else {
      float corr = __builtin_amdgcn_exp2f(mrun - mnew);
      lpart = lpart * corr + rs_local;
      mrun = mnew;
      float c0 = __shfl(corr, lg * 4 + 0);
      float c1 = __shfl(corr, lg * 4 + 1);
      float c2 = __shfl(corr, lg * 4 + 2);
      float c3 = __shfl(corr, lg * 4 + 3);
#pragma unroll
      for (int dt = 0; dt < 4; ++dt) {
        o[dt][0] *= c0; o[dt][1] *= c1; o[dt][2] *= c2; o[dt][3] *= c3;
      }
    }

    // ---- pack P (register-only): pa[k2], k2 = h2*2 + k2' ----
    bf16x8 pa[4];
#pragma unroll
    for (int h2 = 0; h2 < 2; ++h2)
#pragma unroll
      for (int k2p = 0; k2p < 2; ++k2p)
#pragma unroll
        for (int jj = 0; jj < 4; ++jj) {
          pa[h2 * 2 + k2p][jj]     = (bf16)s[h2 * 4 + k2p * 2 + 0][jj];
          pa[h2 * 2 + k2p][4 + jj] = (bf16)s[h2 * 4 + k2p * 2 + 1][jj];
        }

    // ---- PV: 16 MFMA, V fragments streamed per k2 ----
    __builtin_amdgcn_s_setprio(1);
#pragma unroll
    for (int k2 = 0; k2 < 4; ++k2) {
      bf16x8 vf[4];
#pragma unroll
      for (int dt = 0; dt < 4; ++dt)
        vf[dt] = *reinterpret_cast<const bf16x8*>(Vl + ((dt * 4 + k2) * 64 + lane) * 8);
#pragma unroll
      for (int dt = 0; dt < 4; ++dt)
        o[dt] = __builtin_amdgcn_mfma_f32_16x16x32_bf16(pa[k2], vf[dt], o[dt], 0, 0, 0);
    }
    __builtin_amdgcn_s_setprio(0);

    if (notlast) __syncthreads();   // drains this tile's prefetch (already overlapped)
    cur ^= 1;
  }
#undef STAGE_KV

  // epilogue: reduce per-lane partials, normalize, store
  float lsum = lpart;
  lsum += __shfl_xor(lsum, 16);
  lsum += __shfl_xor(lsum, 32);
  const float inv = 1.0f / lsum;               // valid for q = l15
  const float iv0 = __shfl(inv, lg * 4 + 0);
  const float iv1 = __shfl(inv, lg * 4 + 1);
  const float iv2 = __shfl(inv, lg * 4 + 2);
  const float iv3 = __shfl(inv, lg * 4 + 3);

  bf16* Ob = out + (size_t)(b * NQ + qt * 128 + w * 16) * DI + h * DH;
#pragma unroll
  for (int dt = 0; dt < 4; ++dt) {
    Ob[(size_t)(lg * 4 + 0) * DI + dt * 16 + l15] = (bf16)(o[dt][0] * iv0);
    Ob[(size_t)(lg * 4 + 1) * DI + dt * 16 + l15] = (bf16)(o[dt][1] * iv1);
    Ob[(size_t)(lg * 4 + 2) * DI + dt * 16 + l15] = (bf16)(o[dt][2] * iv2);
    Ob[(size_t)(lg * 4 + 3) * DI + dt * 16 + l15] = (bf16)(o[dt][3] * iv3);
  }
}

// ---------------- launch ----------------
extern "C" void kernel_launch(void* const* d_in, const int* in_sizes, int n_in,
                              void* d_out, int out_size, void* d_ws, size_t ws_size,
                              hipStream_t stream) {
  const float* q     = (const float*)d_in[0];
  const float* ctx   = (const float*)d_in[1];
  const float* Wq    = (const float*)d_in[2];
  const float* Wkv   = (const float*)d_in[3];
  const float* Wproj = (const float*)d_in[4];
  const float* bproj = (const float*)d_in[5];
  const float* qg    = (const float*)d_in[6];
  const float* qb    = (const float*)d_in[7];
  const float* cg    = (const float*)d_in[8];
  const float* cb    = (const float*)d_in[9];

  char* ws = (char*)d_ws;
  bf16* qn    = (bf16*)(ws);                       // 8 MB  (4096x1024)
  bf16* cn    = (bf16*)(ws + ( 8ull << 20));       // 16 MB (8192x1024)
  bf16* Wq_b  = (bf16*)(ws + (24ull << 20));       // 2 MB
  bf16* Wkv_b = (bf16*)(ws + (26ull << 20));       // 4 MB
  bf16* Wp_b  = (bf16*)(ws + (30ull << 20));       // 2 MB
  bf16* qpb   = (bf16*)(ws + (32ull << 20));       // 8 MB  (4096x1024)
  bf16* kbuf  = (bf16*)(ws + (40ull << 20));       // 16 MB (B,NKV,DI)
  bf16* vT    = (bf16*)(ws + (56ull << 20));       // 16 MB (B,DI,NKV) swizzled
  bf16* aout  = (bf16*)(ws + (72ull << 20));       // 8 MB  (4096x1024)

  cvt_all<<<4096, 256, 0, stream>>>(Wq, Wkv, Wproj, Wq_b, Wkv_b, Wp_b);
  ln_kernel<<<12288, 256, 0, stream>>>(q, ctx, qg, qb, cg, cb, qn, cn);

  gemm_bt<0, 64><<<512,  256, 0, stream>>>(qn,   Wq_b,  qpb,  nullptr, nullptr, 4096, 1024);
  gemm_bt<1,128><<<1024, 256, 0, stream>>>(cn,   Wkv_b, kbuf, vT,      nullptr, 8192, 2048);

  attn_kernel<<<512, 512, 0, stream>>>(qpb, kbuf, vT, aout);

  gemm_bt<2, 64><<<512,  256, 0, stream>>>(aout, Wp_b,  d_out, nullptr, bproj, 4096, 1024);
}

// Round 8
// 142.707 us; speedup vs baseline: 2.4819x; 1.1479x over previous
//
#include <hip/hip_runtime.h>
#include <hip/hip_bf16.h>
#include <stdint.h>

#define B_N 4
#define NQ 1024
#define NKV 2048
#define DI 1024
#define H 16
#define DH 64

using bf16 = __bf16;
typedef bf16 bf16x8 __attribute__((ext_vector_type(8)));
typedef bf16 bf16x4 __attribute__((ext_vector_type(4)));
typedef float f32x4 __attribute__((ext_vector_type(4)));

typedef const __attribute__((address_space(1))) void* gptr_t;
typedef __attribute__((address_space(3))) void* sptr_t;

// ---------------- fused f32 -> bf16 convert of all three weights ----------------
__global__ __launch_bounds__(256) void cvt_all(const float* __restrict__ Wq,
    const float* __restrict__ Wkv, const float* __restrict__ Wproj,
    bf16* __restrict__ oq, bf16* __restrict__ okv, bf16* __restrict__ op) {
  int i = blockIdx.x * 256 + threadIdx.x;
  const float* src; bf16* dst; int j;
  if (i < 262144)      { src = Wq;    dst = oq;  j = i; }
  else if (i < 786432) { src = Wkv;   dst = okv; j = i - 262144; }
  else                 { src = Wproj; dst = op;  j = i - 786432; }
  float4 v = reinterpret_cast<const float4*>(src)[j];
  bf16x4 o;
  o[0] = (bf16)v.x; o[1] = (bf16)v.y; o[2] = (bf16)v.z; o[3] = (bf16)v.w;
  reinterpret_cast<bf16x4*>(dst)[j] = o;
}

// ---------------- fused LayerNorm (q rows then ctx rows) -> bf16 ----------------
__global__ __launch_bounds__(256) void ln_kernel(const float* __restrict__ q,
    const float* __restrict__ ctx,
    const float* __restrict__ qg, const float* __restrict__ qb,
    const float* __restrict__ cg, const float* __restrict__ cb,
    bf16* __restrict__ qn, bf16* __restrict__ cn) {
  int row = blockIdx.x;
  const float* x; const float* gamma; const float* beta; bf16* out; int r;
  if (row < 4096) { x = q;   gamma = qg; beta = qb; out = qn; r = row; }
  else            { x = ctx; gamma = cg; beta = cb; out = cn; r = row - 4096; }
  int t = threadIdx.x;
  const float4 v = reinterpret_cast<const float4*>(x + (size_t)r * 1024)[t];
  float s = v.x + v.y + v.z + v.w;
  float s2 = v.x*v.x + v.y*v.y + v.z*v.z + v.w*v.w;
#pragma unroll
  for (int m = 1; m < 64; m <<= 1) { s += __shfl_xor(s, m); s2 += __shfl_xor(s2, m); }
  __shared__ float red[8];
  int wid = t >> 6;
  if ((t & 63) == 0) { red[wid] = s; red[wid + 4] = s2; }
  __syncthreads();
  float ts  = red[0] + red[1] + red[2] + red[3];
  float ts2 = red[4] + red[5] + red[6] + red[7];
  float mean = ts * (1.0f / 1024.0f);
  float var  = ts2 * (1.0f / 1024.0f) - mean * mean;
  float rstd = rsqrtf(var + 1e-5f);
  float4 g  = reinterpret_cast<const float4*>(gamma)[t];
  float4 bb = reinterpret_cast<const float4*>(beta)[t];
  bf16x4 o;
  o[0] = (bf16)((v.x - mean) * rstd * g.x + bb.x);
  o[1] = (bf16)((v.y - mean) * rstd * g.y + bb.y);
  o[2] = (bf16)((v.z - mean) * rstd * g.z + bb.z);
  o[3] = (bf16)((v.w - mean) * rstd * g.w + bb.w);
  reinterpret_cast<bf16x4*>(out + (size_t)r * 1024)[t] = o;
}

// ---------------- GEMM: C[m,n] = sum_k A[m,k]*Bm[n,k]  (A: MxK, Bm: NxK, K=1024) ----
// Tile: 128 x BN, BK=64, 4 waves. LDS XOR-swizzled (slot ^= row&7) with
// pre-swizzled global source (linear LDS dest for global_load_lds) + swizzled read.
// XCD-aware bijective block swizzle (grid % 8 == 0).
// MODE 0: bf16 out, * (0.125*log2e) (qp, exp2-domain logits)
// MODE 1: kv split -> out0 = K (B,NKV,DI) bf16, out1 = V^T permuted (B,DI,NKV) bf16
// MODE 2: f32 out + bias (proj)
template<int MODE, int BN>
__global__ __launch_bounds__(256) void gemm_bt(const bf16* __restrict__ A,
    const bf16* __restrict__ Bm, void* __restrict__ out0, void* __restrict__ out1,
    const float* __restrict__ bias, int M, int N) {
  constexpr int K = 1024;
  constexpr int MI = (BN == 128) ? 4 : 2;
  constexpr int NBL = (BN == 128) ? 4 : 2;     // B staging loads/thread
  __shared__ bf16 lA[128 * 64];
  __shared__ bf16 lB[BN * 64];
  // XCD swizzle: consecutive bm-panels stay on one XCD's L2
  const int cpx = gridDim.x >> 3;
  const int bid = (blockIdx.x & 7) * cpx + (blockIdx.x >> 3);
  const int nbn = N / BN;
  const int bm = bid / nbn, bn = bid - bm * nbn;
  const int m0 = bm << 7, n0 = bn * BN;
  const int tid = threadIdx.x;
  const int lane = tid & 63, wid = tid >> 6;
  const int rowb = (BN == 128) ? ((wid >> 1) * 64) : (wid * 32);
  const int colb = (BN == 128) ? ((wid & 1) * 64) : 0;
  const int l15 = lane & 15, lg = lane >> 4;

  f32x4 acc[MI][4] = {};

  // staging: LDS slot s holds global column slot (s&7)^((s>>3)&7) of row s>>3
  const bf16* gA[4]; const bf16* gB[NBL];
#pragma unroll
  for (int u = 0; u < 4; ++u) {
    int s = tid + u * 256;
    int row = s >> 3, c8 = (s & 7) ^ (row & 7);
    gA[u] = A + (size_t)(m0 + row) * K + c8 * 8;
  }
#pragma unroll
  for (int u = 0; u < NBL; ++u) {
    int s = tid + u * 256;
    int row = s >> 3, c8 = (s & 7) ^ (row & 7);
    gB[u] = Bm + (size_t)(n0 + row) * K + c8 * 8;
  }

  const int sw = l15 & 7;   // = row&7 for every fragment row this lane reads

  for (int k0 = 0; k0 < K; k0 += 64) {
#pragma unroll
    for (int u = 0; u < 4; ++u)
      __builtin_amdgcn_global_load_lds((gptr_t)(gA[u] + k0), (sptr_t)(lA + (tid + u * 256) * 8), 16, 0, 0);
#pragma unroll
    for (int u = 0; u < NBL; ++u)
      __builtin_amdgcn_global_load_lds((gptr_t)(gB[u] + k0), (sptr_t)(lB + (tid + u * 256) * 8), 16, 0, 0);
    __syncthreads();
#pragma unroll
    for (int ks2 = 0; ks2 < 2; ++ks2) {
      const int soff = ((ks2 * 4 + lg) ^ sw) * 8;   // swizzled 16B-slot within row
      bf16x8 af[MI], bfr[4];
#pragma unroll
      for (int i = 0; i < MI; ++i)
        af[i]  = *reinterpret_cast<const bf16x8*>(lA + (rowb + i * 16 + l15) * 64 + soff);
#pragma unroll
      for (int j = 0; j < 4; ++j)
        bfr[j] = *reinterpret_cast<const bf16x8*>(lB + (colb + j * 16 + l15) * 64 + soff);
#pragma unroll
      for (int i = 0; i < MI; ++i)
#pragma unroll
        for (int j = 0; j < 4; ++j)
          acc[i][j] = __builtin_amdgcn_mfma_f32_16x16x32_bf16(af[i], bfr[j], acc[i][j], 0, 0, 0);
    }
    __syncthreads();
  }

  const int mB = m0 + rowb + lg * 4;      // + i*16 + r
  const int nB = n0 + colb + l15;         // + j*16
  if constexpr (MODE == 0) {
    bf16* o = reinterpret_cast<bf16*>(out0);
    constexpr float SC = 0.125f * 1.44269504089f;  // DH^-0.5 * log2(e)
#pragma unroll
    for (int i = 0; i < MI; ++i)
#pragma unroll
      for (int j = 0; j < 4; ++j)
#pragma unroll
        for (int r = 0; r < 4; ++r)
          o[(size_t)(mB + i * 16 + r) * N + nB + j * 16] = (bf16)(acc[i][j][r] * SC);
  } else if constexpr (MODE == 2) {
    float* o = reinterpret_cast<float*>(out0);
#pragma unroll
    for (int j = 0; j < 4; ++j) {
      float bj = bias[nB + j * 16];
#pragma unroll
      for (int i = 0; i < MI; ++i)
#pragma unroll
        for (int r = 0; r < 4; ++r)
          o[(size_t)(mB + i * 16 + r) * N + nB + j * 16] = acc[i][j][r] + bj;
    }
  } else {
    if (n0 < 1024) {  // K part: (B,NKV,DI) flat = m*1024 + n
      bf16* o = reinterpret_cast<bf16*>(out0);
#pragma unroll
      for (int i = 0; i < MI; ++i)
#pragma unroll
        for (int j = 0; j < 4; ++j)
#pragma unroll
          for (int r = 0; r < 4; ++r)
            o[(size_t)(mB + i * 16 + r) * 1024 + nB + j * 16] = (bf16)acc[i][j][r];
    } else {          // V part: transposed (B,DI,NKV) with in-64 column swizzle
      bf16* o = reinterpret_cast<bf16*>(out1);
#pragma unroll
      for (int i = 0; i < MI; ++i) {
        int m = mB + i * 16;            // global row = b*2048 + kv  (kv mult of 4)
        int bb_ = m >> 11, kv = m & 2047;
        int u = kv & 63;
        // c = k2*32 + lg*8 + j2*4 + j1  from  kv = k2*32 + j2*16 + lg*4 + j1
        int c = (u & 32) | ((u & 12) << 1) | ((u & 16) >> 2) | (u & 3);
        int col = (kv & ~63) | c;
#pragma unroll
        for (int j = 0; j < 4; ++j) {
          int nv = nB + j * 16 - 1024;  // d index within DI
          bf16x4 pk;
          pk[0] = (bf16)acc[i][j][0]; pk[1] = (bf16)acc[i][j][1];
          pk[2] = (bf16)acc[i][j][2]; pk[3] = (bf16)acc[i][j][3];
          *reinterpret_cast<bf16x4*>(o + ((size_t)(bb_ << 10) + nv) * 2048 + col) = pk;
        }
      }
    }
  }
}

// ---------------- Flash attention v7: LDS-staged K/V, KVBLK=128, 8 waves x 16q ----------------
// S^T = mfma(K, Q): lane holds S[q = lane&15][kv = ni*16 + lg*4 + r] (exp2-domain logits).
// K/V tiles staged to LDS in fragment-slot-major order (16B slot = frag*64 + lane);
// stage source addresses carry the inverse permutation (pre-swizzled-source, linear LDS).
// 128-kv tile = two 64-groups; the V in-64 column swizzle applies per group.
__global__ __launch_bounds__(512, 4) void attn_kernel(const bf16* __restrict__ qp,
    const bf16* __restrict__ kk, const bf16* __restrict__ vTp, bf16* __restrict__ out) {
  __shared__ bf16 smem[32768];   // [K dbuf 2x8192][V dbuf 2x8192]  (64 KB)
  // XCD-aware bijective remap: the 8 q-tiles of one (b,h) land on one XCD
  const int pos = blockIdx.x;
  const int idx = pos >> 3;
  const int bh = ((idx >> 3) << 3) | (pos & 7);
  const int qt = idx & 7;
  const int b = bh >> 4, h = bh & 15;
  const int tid = threadIdx.x;              // 0..511
  const int lane = tid & 63, w = tid >> 6;  // 8 waves
  const int l15 = lane & 15, lg = lane >> 4;

  const bf16* Qb = qp + (size_t)(b * NQ + qt * 128 + w * 16) * DI + h * DH;
  const bf16* Kb = kk + (size_t)b * NKV * DI + h * DH;
  const bf16* Vb = vTp + (size_t)(b * DI + h * DH) * NKV;

  // K slots (1024 x 16B): bits [9:7]=ni, [6]=ks, [5:4]=lg, [3:0]=l15
  // V slots (1024 x 16B): bits [9:8]=dt, [7:6]=k2, [5:4]=lg, [3:0]=l15
  const int sA = tid, sB = tid + 512;
  const int rKA = ((sA >> 7) << 4) | (sA & 15), cKA = ((sA >> 4) & 7) * 8;
  const int rKB = ((sB >> 7) << 4) | (sB & 15), cKB = ((sB >> 4) & 7) * 8;
  const int rVA = ((sA >> 8) << 4) | (sA & 15), cVA = ((sA >> 6) & 3) * 32 + ((sA >> 4) & 3) * 8;
  const int rVB = ((sB >> 8) << 4) | (sB & 15), cVB = ((sB >> 6) & 3) * 32 + ((sB >> 4) & 3) * 8;
  const bf16* pKA = Kb + (size_t)rKA * DI + cKA;   // + kv0*DI per tile
  const bf16* pKB = Kb + (size_t)rKB * DI + cKB;
  const bf16* pVA = Vb + (size_t)rVA * NKV + cVA;  // + kv0 per tile
  const bf16* pVB = Vb + (size_t)rVB * NKV + cVB;

#define STAGE_KV(bufsel, kv)                                                                        \
  do {                                                                                              \
    __builtin_amdgcn_global_load_lds((gptr_t)(pKA + (size_t)(kv) * DI),                             \
                                     (sptr_t)(smem + (bufsel) * 8192 + sA * 8), 16, 0, 0);          \
    __builtin_amdgcn_global_load_lds((gptr_t)(pKB + (size_t)(kv) * DI),                             \
                                     (sptr_t)(smem + (bufsel) * 8192 + sB * 8), 16, 0, 0);          \
    __builtin_amdgcn_global_load_lds((gptr_t)(pVA + (kv)),                                          \
                                     (sptr_t)(smem + 16384 + (bufsel) * 8192 + sA * 8), 16, 0, 0);  \
    __builtin_amdgcn_global_load_lds((gptr_t)(pVB + (kv)),                                          \
                                     (sptr_t)(smem + 16384 + (bufsel) * 8192 + sB * 8), 16, 0, 0);  \
  } while (0)

  bf16x8 qf[2];
#pragma unroll
  for (int ks = 0; ks < 2; ++ks)
    qf[ks] = *reinterpret_cast<const bf16x8*>(Qb + (size_t)l15 * DI + ks * 32 + lg * 8);

  f32x4 o[4] = {};
  float mrun = -1e30f;
  float lpart = 0.0f;    // per-lane partial row-sum (reduced across lg at epilogue)

  STAGE_KV(0, 0);
  __syncthreads();
  int cur = 0;

  for (int kv0 = 0; kv0 < NKV; kv0 += 128) {
    const bool notlast = (kv0 + 128 < NKV);
    if (notlast) STAGE_KV(cur ^ 1, kv0 + 128);   // issue early; drained by tile-end barrier

    const bf16* Kl = smem + cur * 8192;
    const bf16* Vl = smem + 16384 + cur * 8192;

    // ---- QK^T (swapped operands), two 64-kv groups ----
    f32x4 s[8] = {};
#pragma unroll
    for (int h2 = 0; h2 < 2; ++h2) {
      bf16x8 kf[4][2];
#pragma unroll
      for (int ni = 0; ni < 4; ++ni)
#pragma unroll
        for (int ks = 0; ks < 2; ++ks)
          kf[ni][ks] = *reinterpret_cast<const bf16x8*>(Kl + (((h2 * 4 + ni) * 2 + ks) * 64 + lane) * 8);
      __builtin_amdgcn_s_setprio(1);
#pragma unroll
      for (int ni = 0; ni < 4; ++ni)
#pragma unroll
        for (int ks = 0; ks < 2; ++ks)
          s[h2 * 4 + ni] = __builtin_amdgcn_mfma_f32_16x16x32_bf16(kf[ni][ks], qf[ks], s[h2 * 4 + ni], 0, 0, 0);
      __builtin_amdgcn_s_setprio(0);
    }

    // ---- softmax (per q = l15; exp2 domain) ----
    f32x4 mv = s[0];
#pragma unroll
    for (int i = 1; i < 8; ++i) {
      mv[0] = fmaxf(mv[0], s[i][0]); mv[1] = fmaxf(mv[1], s[i][1]);
      mv[2] = fmaxf(mv[2], s[i][2]); mv[3] = fmaxf(mv[3], s[i][3]);
    }
    float pm = fmaxf(fmaxf(mv[0], mv[1]), fmaxf(mv[2], mv[3]));
    pm = fmaxf(pm, __shfl_xor(pm, 16));
    pm = fmaxf(pm, __shfl_xor(pm, 32));

    const bool noresc = __all(pm <= mrun);   // exact: corr == 1 when no new max
    const float mnew = noresc ? mrun : fmaxf(mrun, pm);

    f32x4 sv = {};
#pragma unroll
    for (int i = 0; i < 8; ++i) {
#pragma unroll
      for (int r = 0; r < 4; ++r) {
        s[i][r] = __builtin_amdgcn_exp2f(s[i][r] - mnew);
        sv[r] += s[i][r];
      }
    }
    const float rs_local = (sv[0] + sv[1]) + (sv[2] + sv[3]);

    if (noresc) {
      lpart += rs_local;
    } else {
      float corr = __builtin_amdgcn_exp2f(mrun - mnew);
      lpart = lpart * corr + rs_local;
      mrun = mnew;
      float c0 = __shfl(corr, lg * 4 + 0);
      float c1 = __shfl(corr, lg * 4 + 1);
      float c2 = __shfl(corr, lg * 4 + 2);
      float c3 = __shfl(corr, lg * 4 + 3);
#pragma unroll
      for (int dt = 0; dt < 4; ++dt) {
        o[dt][0] *= c0; o[dt][1] *= c1; o[dt][2] *= c2; o[dt][3] *= c3;
      }
    }

    // ---- pack P (register-only): pa[k2], k2 = h2*2 + k2' ----
    bf16x8 pa[4];
#pragma unroll
    for (int h2 = 0; h2 < 2; ++h2)
#pragma unroll
      for (int k2p = 0; k2p < 2; ++k2p)
#pragma unroll
        for (int jj = 0; jj < 4; ++jj) {
          pa[h2 * 2 + k2p][jj]     = (bf16)s[h2 * 4 + k2p * 2 + 0][jj];
          pa[h2 * 2 + k2p][4 + jj] = (bf16)s[h2 * 4 + k2p * 2 + 1][jj];
        }

    // ---- PV: 16 MFMA, V fragments streamed per k2 ----
    __builtin_amdgcn_s_setprio(1);
#pragma unroll
    for (int k2 = 0; k2 < 4; ++k2) {
      bf16x8 vf[4];
#pragma unroll
      for (int dt = 0; dt < 4; ++dt)
        vf[dt] = *reinterpret_cast<const bf16x8*>(Vl + ((dt * 4 + k2) * 64 + lane) * 8);
#pragma unroll
      for (int dt = 0; dt < 4; ++dt)
        o[dt] = __builtin_amdgcn_mfma_f32_16x16x32_bf16(pa[k2], vf[dt], o[dt], 0, 0, 0);
    }
    __builtin_amdgcn_s_setprio(0);

    if (notlast) __syncthreads();   // drains this tile's prefetch (already overlapped)
    cur ^= 1;
  }
#undef STAGE_KV

  // epilogue: reduce per-lane partials, normalize, store
  float lsum = lpart;
  lsum += __shfl_xor(lsum, 16);
  lsum += __shfl_xor(lsum, 32);
  const float inv = 1.0f / lsum;               // valid for q = l15
  const float iv0 = __shfl(inv, lg * 4 + 0);
  const float iv1 = __shfl(inv, lg * 4 + 1);
  const float iv2 = __shfl(inv, lg * 4 + 2);
  const float iv3 = __shfl(inv, lg * 4 + 3);

  bf16* Ob = out + (size_t)(b * NQ + qt * 128 + w * 16) * DI + h * DH;
#pragma unroll
  for (int dt = 0; dt < 4; ++dt) {
    Ob[(size_t)(lg * 4 + 0) * DI + dt * 16 + l15] = (bf16)(o[dt][0] * iv0);
    Ob[(size_t)(lg * 4 + 1) * DI + dt * 16 + l15] = (bf16)(o[dt][1] * iv1);
    Ob[(size_t)(lg * 4 + 2) * DI + dt * 16 + l15] = (bf16)(o[dt][2] * iv2);
    Ob[(size_t)(lg * 4 + 3) * DI + dt * 16 + l15] = (bf16)(o[dt][3] * iv3);
  }
}

// ---------------- launch ----------------
extern "C" void kernel_launch(void* const* d_in, const int* in_sizes, int n_in,
                              void* d_out, int out_size, void* d_ws, size_t ws_size,
                              hipStream_t stream) {
  const float* q     = (const float*)d_in[0];
  const float* ctx   = (const float*)d_in[1];
  const float* Wq    = (const float*)d_in[2];
  const float* Wkv   = (const float*)d_in[3];
  const float* Wproj = (const float*)d_in[4];
  const float* bproj = (const float*)d_in[5];
  const float* qg    = (const float*)d_in[6];
  const float* qb    = (const float*)d_in[7];
  const float* cg    = (const float*)d_in[8];
  const float* cb    = (const float*)d_in[9];

  char* ws = (char*)d_ws;
  bf16* qn    = (bf16*)(ws);                       // 8 MB  (4096x1024)
  bf16* cn    = (bf16*)(ws + ( 8ull << 20));       // 16 MB (8192x1024)
  bf16* Wq_b  = (bf16*)(ws + (24ull << 20));       // 2 MB
  bf16* Wkv_b = (bf16*)(ws + (26ull << 20));       // 4 MB
  bf16* Wp_b  = (bf16*)(ws + (30ull << 20));       // 2 MB
  bf16* qpb   = (bf16*)(ws + (32ull << 20));       // 8 MB  (4096x1024)
  bf16* kbuf  = (bf16*)(ws + (40ull << 20));       // 16 MB (B,NKV,DI)
  bf16* vT    = (bf16*)(ws + (56ull << 20));       // 16 MB (B,DI,NKV) swizzled
  bf16* aout  = (bf16*)(ws + (72ull << 20));       // 8 MB  (4096x1024)

  cvt_all<<<4096, 256, 0, stream>>>(Wq, Wkv, Wproj, Wq_b, Wkv_b, Wp_b);
  ln_kernel<<<12288, 256, 0, stream>>>(q, ctx, qg, qb, cg, cb, qn, cn);

  gemm_bt<0, 64><<<512,  256, 0, stream>>>(qn,   Wq_b,  qpb,  nullptr, nullptr, 4096, 1024);
  gemm_bt<1,128><<<1024, 256, 0, stream>>>(cn,   Wkv_b, kbuf, vT,      nullptr, 8192, 2048);

  attn_kernel<<<512, 512, 0, stream>>>(qpb, kbuf, vT, aout);

  gemm_bt<2, 64><<<512,  256, 0, stream>>>(aout, Wp_b,  d_out, nullptr, bproj, 4096, 1024);
}